// Round 19
// baseline (229.682 us; speedup 1.0000x reference)
//
#include <hip/hip_runtime.h>

// GraphNetworkLayer: B=8, N=4096, E=16384, G=64, D=128, fp32 in/out.
// Round 19: R18 config with ONE delta — prep_all streaming regions widened
// to 4 short8-chunks per thread (8 independent float4 loads in flight;
// was 2 dependent loads -> pure latency exposure, 1.5 TB/s). idx copy is
// int4->float4. Weights gather + histogram tail unchanged. Grid 3944.
// All other kernels byte-identical to R18 (edge 49us validated).

#define DD 128
typedef unsigned short u16;
typedef __attribute__((ext_vector_type(8))) short short8;   // 8 bf16
typedef __attribute__((ext_vector_type(4))) short s16x4;    // 4 bf16
typedef __attribute__((ext_vector_type(4))) float f32x4;

constexpr int B_ = 8, N_ = 4096, E_ = 16384, G_ = 64;
constexpr int NODES_SZ = B_ * N_ * DD;   // 4,194,304
constexpr int EDGES_SZ = B_ * E_ * DD;   // 16,777,216
constexpr int BE_ = B_ * E_;             // 131,072
constexpr int BN_ = B_ * N_;             // 32,768
constexpr int BG_ = B_ * G_;             // 512
constexpr int GLOB_SZ = BG_ * DD;        // 65,536
constexpr int PART = 4;

constexpr int OFF_NODES = 0;
constexpr int OFF_EDGES = OFF_NODES + NODES_SZ;
constexpr int OFF_RECV  = OFF_EDGES + EDGES_SZ;
constexpr int OFF_SEND  = OFF_RECV + BE_;
constexpr int OFF_GLOB  = OFF_SEND + BE_;
constexpr int OFF_NGI   = OFF_GLOB + GLOB_SZ;
constexpr int OFF_EGI   = OFF_NGI + BN_;

// prep_all region boundaries (thread indices)
constexpr int NT_CH   = NODES_SZ / 8;                // 524288 nodes chunks
constexpr int GL_CH   = GLOB_SZ / 8;                 // 8192 glob chunks
constexpr int RW_END  = 114688;                      // weights (1/thread)
constexpr int RB_END  = RW_END + (NT_CH + GL_CH) / 4;   // +133120 = 247808
constexpr int RC_END  = RB_END + (EDGES_SZ / 8) / 4;    // +524288 = 772096
constexpr int RD_END  = RC_END + (3 * BE_ + BN_) / 4;   // +106496 = 878592
constexpr int RE_END  = RD_END + BE_;                   // +131072 = 1009664
// grid = RE_END / 256 = 3944 (exact)

// ws layout (float-element offsets) — R15/R18 layout
constexpr int WS_EAGGP = 0;                          // [PART][BG][DD] f32
constexpr int WS_NAGGP = WS_EAGGP + PART * GLOB_SZ;
constexpr int WS_CNT   = WS_NAGGP + PART * GLOB_SZ;  // int [B*N] (memset 0)
constexpr int WS_GCNTE = WS_CNT + BN_;               // int [512] (memset 0)
constexpr int WS_GCNTN = WS_GCNTE + 512;             // int [512] (memset 0)
constexpr int WS_CUR   = WS_GCNTN + 512;             // int [B*N]
constexpr int WS_GCURE = WS_CUR + BN_;               // int [512]
constexpr int WS_GCURN = WS_GCURE + 512;             // int [512]
constexpr int WS_ELIST = WS_GCURN + 512;             // int [B*E]
constexpr int WS_GELE  = WS_ELIST + BE_;             // int [B*E]
constexpr int WS_GELN  = WS_GELE + BE_;              // int [B*N]
constexpr int WS_ADJB  = WS_GELN + BN_;              // (unused)
constexpr int WS_NODB  = WS_ADJB + (BN_ * DD) / 2;   // u16 [B,N,D]
constexpr int WS_GLOBB = WS_NODB + (BN_ * DD) / 2;   // u16 [B,G,D]
constexpr int WS_WET   = WS_GLOBB + GLOB_SZ / 2;     // u16 [128*512] swz image
constexpr int WS_WNT   = WS_WET + 32768;             // u16 [128*384] swz image
constexpr int WS_UEB   = WS_WNT + 24576;             // u16 [B,E,D] bf16 u_e
constexpr int WS_EDGB  = WS_UEB + (BE_ * DD) / 2;    // u16 [B,E,D] edgesB; uNb aliases

__device__ inline u16 f2bf(float f) {
    union { float f; unsigned u; } v; v.f = f;
    return (u16)((v.u + 0x7fffu + ((v.u >> 16) & 1u)) >> 16);
}
__device__ inline float bf2f(u16 h) {
    union { unsigned u; float f; } v; v.u = ((unsigned)h) << 16; return v.f;
}
__device__ inline short8 pack8(float4 a, float4 b) {
    short8 r;
    r[0] = (short)f2bf(a.x); r[1] = (short)f2bf(a.y);
    r[2] = (short)f2bf(a.z); r[3] = (short)f2bf(a.w);
    r[4] = (short)f2bf(b.x); r[5] = (short)f2bf(b.y);
    r[6] = (short)f2bf(b.z); r[7] = (short)f2bf(b.w);
    return r;
}

// -------- fused prep + histogram tail; streaming regions 4 chunks/thread --
__global__ __launch_bounds__(256) void prep_all(
    const float* __restrict__ We, const float* __restrict__ Wn,
    u16* __restrict__ WeT2, u16* __restrict__ WnT2,
    const float* __restrict__ nodes, const float* __restrict__ glob,
    const float* __restrict__ edges,
    u16* __restrict__ nodesB, u16* __restrict__ globB, u16* __restrict__ edgesB,
    const int* __restrict__ recv, const int* __restrict__ send,
    const int* __restrict__ ngi, const int* __restrict__ egi,
    float* __restrict__ out,
    int* __restrict__ cnt, int* __restrict__ gcnt_e, int* __restrict__ gcnt_n) {
    const int i = blockIdx.x * 256 + threadIdx.x;
    if (i < RW_END) {
        // weights -> pre-swizzled bf16 images (scattered gather, 1/thread)
        if (i < 65536) {
            const int ch = i >> 15;
            const int r = i & 32767;
            const int row = r >> 9;
            const int inb = (r << 1) & 1023;
            const int kb = inb ^ ((row & 7) << 4);
            WeT2[i] = f2bf(We[(kb >> 1) * DD + ch * 64 + row]);
        } else {
            const int q = i - 65536;
            const int ch = q / 24576;
            const int r = q % 24576;
            const int row = r / 384;
            const int inb = (r % 384) << 1;
            const int kb = inb ^ ((row & 7) << 4);
            WnT2[q] = f2bf(Wn[(kb >> 1) * DD + ch * 64 + row]);
        }
    } else if (i < RB_END) {
        // nodes+glob cast: 4 chunks (32 bf16) per thread, 8 indep float4 loads
        const long c0 = ((long)(i - RW_END)) << 2;
        if (c0 < NT_CH) {
            float4 a[4], b[4];
            #pragma unroll
            for (int t = 0; t < 4; ++t) {
                a[t] = *(const float4*)(nodes + (c0 + t) * 8);
                b[t] = *(const float4*)(nodes + (c0 + t) * 8 + 4);
            }
            #pragma unroll
            for (int t = 0; t < 4; ++t)
                *(short8*)(nodesB + (c0 + t) * 8) = pack8(a[t], b[t]);
        } else {
            const long c2 = c0 - NT_CH;
            float4 a[4], b[4];
            #pragma unroll
            for (int t = 0; t < 4; ++t) {
                a[t] = *(const float4*)(glob + (c2 + t) * 8);
                b[t] = *(const float4*)(glob + (c2 + t) * 8 + 4);
            }
            #pragma unroll
            for (int t = 0; t < 4; ++t)
                *(short8*)(globB + (c2 + t) * 8) = pack8(a[t], b[t]);
        }
    } else if (i < RC_END) {
        // edges cast: 4 chunks per thread (128B read / 64B write, contiguous)
        const long c0 = ((long)(i - RB_END)) << 2;
        float4 a[4], b[4];
        #pragma unroll
        for (int t = 0; t < 4; ++t) {
            a[t] = *(const float4*)(edges + (c0 + t) * 8);
            b[t] = *(const float4*)(edges + (c0 + t) * 8 + 4);
        }
        #pragma unroll
        for (int t = 0; t < 4; ++t)
            *(short8*)(edgesB + (c0 + t) * 8) = pack8(a[t], b[t]);
    } else if (i < RD_END) {
        // idx passthrough: 4 ints per thread (segments are 4-aligned)
        const int k = (i - RC_END) << 2;
        const int* src;
        long dst;
        int loc;
        if (k < BE_)                 { src = recv; loc = k;               dst = OFF_RECV + loc; }
        else if (k < 2 * BE_)        { src = send; loc = k - BE_;         dst = OFF_SEND + loc; }
        else if (k < 2 * BE_ + BN_)  { src = ngi;  loc = k - 2 * BE_;     dst = OFF_NGI + loc; }
        else                         { src = egi;  loc = k - 2 * BE_ - BN_; dst = OFF_EGI + loc; }
        const int4 v = *(const int4*)(src + loc);
        float4 o;
        o.x = (float)v.x; o.y = (float)v.y; o.z = (float)v.z; o.w = (float)v.w;
        *(float4*)(out + dst) = o;
    } else {
        // histogram tail (cnt/gcnt pre-zeroed by memset)
        const int k3 = i - RD_END;                  // < BE_
        const int b = k3 >> 14;
        atomicAdd(&cnt[b * N_ + recv[k3]], 1);
        atomicAdd(&gcnt_e[b * G_ + egi[k3]], 1);
        if (k3 < BN_) atomicAdd(&gcnt_n[(k3 >> 12) * G_ + ngi[k3]], 1);
    }
}

__global__ __launch_bounds__(1024) void k_scan(
    const int* __restrict__ cnt, int* __restrict__ cur,
    const int* __restrict__ gcnt_e, int* __restrict__ gcur_e,
    const int* __restrict__ gcnt_n, int* __restrict__ gcur_n) {
    __shared__ int s[1024];
    const int b = blockIdx.x;
    const int t = threadIdx.x;
    const int base = b * N_;
    int c[4];
    int sum = 0;
    #pragma unroll
    for (int i = 0; i < 4; ++i) { c[i] = cnt[base + 4 * t + i]; sum += c[i]; }
    s[t] = sum;
    __syncthreads();
    for (int off = 1; off < 1024; off <<= 1) {
        int v = s[t];
        if (t >= off) v += s[t - off];
        __syncthreads();
        s[t] = v;
        __syncthreads();
    }
    int eb = s[t] - sum;
    #pragma unroll
    for (int i = 0; i < 4; ++i) { cur[base + 4 * t + i] = eb; eb += c[i]; }
    __syncthreads();
    int gv = 0;
    if (t < G_) { gv = gcnt_e[b * G_ + t]; s[t] = gv; }
    __syncthreads();
    for (int off = 1; off < G_; off <<= 1) {
        int v = 0;
        if (t < G_) { v = s[t]; if (t >= off) v += s[t - off]; }
        __syncthreads();
        if (t < G_) s[t] = v;
        __syncthreads();
    }
    if (t < G_) gcur_e[b * G_ + t] = s[t] - gv;
    __syncthreads();
    if (t < G_) { gv = gcnt_n[b * G_ + t]; s[t] = gv; }
    __syncthreads();
    for (int off = 1; off < G_; off <<= 1) {
        int v = 0;
        if (t < G_) { v = s[t]; if (t >= off) v += s[t - off]; }
        __syncthreads();
        if (t < G_) s[t] = v;
        __syncthreads();
    }
    if (t < G_) gcur_n[b * G_ + t] = s[t] - gv;
}

__global__ __launch_bounds__(256) void k_fill_all(
    const int* __restrict__ recv, const int* __restrict__ egi,
    const int* __restrict__ ngi,
    int* __restrict__ cur, int* __restrict__ elist,
    int* __restrict__ gcur_e, int* __restrict__ gelist_e,
    int* __restrict__ gcur_n, int* __restrict__ gelist_n) {
    const int i = blockIdx.x * 256 + threadIdx.x;
    const int b = i >> 14;
    const int s1 = atomicAdd(&cur[b * N_ + recv[i]], 1);
    elist[b * E_ + s1] = i;
    const int s2 = atomicAdd(&gcur_e[b * G_ + egi[i]], 1);
    gelist_e[b * E_ + s2] = i;
    if (i < BN_) {
        const int b2 = i >> 12;
        const int s3 = atomicAdd(&gcur_n[b2 * G_ + ngi[i]], 1);
        gelist_n[b2 * N_ + s3] = i;
    }
}

// -------- edge GEMM: UNCHANGED (R15: 128x64, M-rep 2, K-step 64, dbuf) ----
__global__ __launch_bounds__(256, 3) void edge_mfma(
    const u16* __restrict__ edgesB, const u16* __restrict__ nodesB,
    const u16* __restrict__ globB,
    const int* __restrict__ receivers, const int* __restrict__ senders,
    const int* __restrict__ egi,
    const u16* __restrict__ WeT2, const float* __restrict__ be,
    const float* __restrict__ w_res,
    float* __restrict__ outE, u16* __restrict__ uEb) {
    __shared__ u16 As[2][128 * 64];            // 2 x 16 KB (rows x 128B)
    __shared__ u16 Bs[2][64 * 64];             // 2 x 8 KB  (cols x 128B)
    const int tid = threadIdx.x;
    const int bid = blockIdx.x;                // 2048
    const int bb = bid & 7;                    // batch = XCD
    const int q = bid >> 3;                    // 0..255
    const int ch = q & 1;
    const int rt = q >> 1;                     // 0..127
    const int row0 = bb * E_ + rt * 128;

    const int wv = tid >> 6, l = tid & 63;
    const int fr = l & 15, fg = l >> 4;
    const int lrow0 = wv * 32 + fr;            // 0..127
    const int R0 = row0 + lrow0, R1 = R0 + 16;

    const char* img = (const char*)(WeT2 + (long)ch * 32768);
    const int swz = (fr & 7) << 4;

    auto stage = [&](int kk, int buf) {
        const int seg = kk >> 1, half = kk & 1;
        #pragma unroll
        for (int i = 0; i < 4; ++i) {          // A: 1024 chunks of 16B
            const int gci = i * 256 + tid;
            const int r = gci >> 3, j = gci & 7;
            const int gr = row0 + r;
            const u16* rp;
            if (seg == 0)      rp = edgesB + (long)gr * DD;
            else if (seg == 1) rp = nodesB + ((long)bb * N_ + senders[gr]) * DD;
            else if (seg == 2) rp = nodesB + ((long)bb * N_ + receivers[gr]) * DD;
            else               rp = globB + ((long)bb * G_ + egi[gr]) * DD;
            const char* src = (const char*)rp + half * 128 +
                              ((j * 16) ^ ((r & 7) << 4));
            char* dst = (char*)As[buf] + r * 128 + j * 16;
            __builtin_amdgcn_global_load_lds(
                (const __attribute__((address_space(1))) void*)src,
                (__attribute__((address_space(3))) void*)dst, 16, 0, 0);
        }
        #pragma unroll
        for (int i = 0; i < 2; ++i) {          // B: 512 chunks of 16B
            const int gci = i * 256 + tid;
            const int col = gci >> 3, j = gci & 7;
            const char* src = img + (long)col * 1024 + kk * 128 + j * 16;
            char* dst = (char*)Bs[buf] + col * 128 + j * 16;
            __builtin_amdgcn_global_load_lds(
                (const __attribute__((address_space(1))) void*)src,
                (__attribute__((address_space(3))) void*)dst, 16, 0, 0);
        }
    };

    f32x4 acc0[4], acc1[4];
    const f32x4 fz = {0.f, 0.f, 0.f, 0.f};
    #pragma unroll
    for (int i = 0; i < 4; ++i) { acc0[i] = fz; acc1[i] = fz; }
    s16x4 eres0[4], eres1[4];

    stage(0, 0);
    __syncthreads();

    #pragma unroll
    for (int kk = 0; kk < 8; ++kk) {
        const int buf = kk & 1;
        if (kk < 7) {
            stage(kk + 1, buf ^ 1);
            __builtin_amdgcn_sched_barrier(0);
        }
        __builtin_amdgcn_s_setprio(1);
        #pragma unroll
        for (int ss = 0; ss < 2; ++ss) {
            const int ko = (ss * 64 + fg * 16) ^ swz;
            const short8 a0 = *(const short8*)((char*)As[buf] + lrow0 * 128 + ko);
            const short8 a1 = *(const short8*)((char*)As[buf] + (lrow0 + 16) * 128 + ko);
            #pragma unroll
            for (int nt = 0; nt < 4; ++nt) {
                const short8 b = *(const short8*)((char*)Bs[buf] + (nt * 16 + fr) * 128 + ko);
                acc0[nt] = __builtin_amdgcn_mfma_f32_16x16x32_bf16(b, a0, acc0[nt], 0, 0, 0);
                acc1[nt] = __builtin_amdgcn_mfma_f32_16x16x32_bf16(b, a1, acc1[nt], 0, 0, 0);
            }
        }
        __builtin_amdgcn_s_setprio(0);
        if (kk == ch) {
            #pragma unroll
            for (int nt = 0; nt < 4; ++nt) {
                const int jb = (nt * 32 + fg * 8) ^ swz;
                eres0[nt] = *(const s16x4*)((char*)As[buf] + lrow0 * 128 + jb);
                eres1[nt] = *(const s16x4*)((char*)As[buf] + (lrow0 + 16) * 128 + jb);
            }
        }
        if (kk < 7) __syncthreads();
    }

    const float wr = w_res[0];
    #pragma unroll
    for (int nt = 0; nt < 4; ++nt) {
        const int c = ch * 64 + nt * 16 + fg * 4;
        const float4 bv = *(const float4*)(be + c);
        const float u00 = fmaxf(acc0[nt][0] + bv.x, 0.f);
        const float u01 = fmaxf(acc0[nt][1] + bv.y, 0.f);
        const float u02 = fmaxf(acc0[nt][2] + bv.z, 0.f);
        const float u03 = fmaxf(acc0[nt][3] + bv.w, 0.f);
        const float u10 = fmaxf(acc1[nt][0] + bv.x, 0.f);
        const float u11 = fmaxf(acc1[nt][1] + bv.y, 0.f);
        const float u12 = fmaxf(acc1[nt][2] + bv.z, 0.f);
        const float u13 = fmaxf(acc1[nt][3] + bv.w, 0.f);
        s16x4 h0, h1;
        h0[0] = (short)f2bf(u00); h0[1] = (short)f2bf(u01);
        h0[2] = (short)f2bf(u02); h0[3] = (short)f2bf(u03);
        h1[0] = (short)f2bf(u10); h1[1] = (short)f2bf(u11);
        h1[2] = (short)f2bf(u12); h1[3] = (short)f2bf(u13);
        *(s16x4*)(uEb + (long)R0 * DD + c) = h0;
        *(s16x4*)(uEb + (long)R1 * DD + c) = h1;
        float4 o0, o1;
        o0.x = bf2f((u16)eres0[nt][0]) + wr * u00;
        o0.y = bf2f((u16)eres0[nt][1]) + wr * u01;
        o0.z = bf2f((u16)eres0[nt][2]) + wr * u02;
        o0.w = bf2f((u16)eres0[nt][3]) + wr * u03;
        o1.x = bf2f((u16)eres1[nt][0]) + wr * u10;
        o1.y = bf2f((u16)eres1[nt][1]) + wr * u11;
        o1.z = bf2f((u16)eres1[nt][2]) + wr * u12;
        o1.w = bf2f((u16)eres1[nt][3]) + wr * u13;
        *(float4*)(outE + (long)R0 * DD + c) = o0;
        *(float4*)(outE + (long)R1 * DD + c) = o1;
    }
}

// -------- merged: node GEMM (blocks 0..511) + eagg gather (512..2559) -----
__global__ __launch_bounds__(256, 3) void node_agge(
    const u16* __restrict__ nodesB, const u16* __restrict__ uEb,
    const u16* __restrict__ globB, const int* __restrict__ ngi,
    const int* __restrict__ cnt, const int* __restrict__ cur,
    const int* __restrict__ elist,
    const u16* __restrict__ WnT2, const float* __restrict__ bn,
    const float* __restrict__ nodes, const float* __restrict__ w_res,
    float* __restrict__ outN, u16* __restrict__ uNb,
    const int* __restrict__ gcnt_e, const int* __restrict__ gcur_e,
    const int* __restrict__ gelist_e, float* __restrict__ eaggp) {
    __shared__ char smem[64 * 384 * 2];        // 48 KB (union)
    const int tid = threadIdx.x;

    if (blockIdx.x >= 512) {
        float* accl = (float*)smem;
        const int abid = blockIdx.x - 512;     // 0..2047
        const int bg = abid >> 2;
        const int p  = abid & 3;
        const int b = bg >> 6;
        const int c4 = (tid & 31) << 2;
        const int sub = tid >> 5;
        const int m = gcnt_e[bg];
        const int* lp = gelist_e + (long)b * E_ + (gcur_e[bg] - m);
        f32x4 acc = {0.f, 0.f, 0.f, 0.f};
        for (int j = p * 8 + sub; j < m; j += 32) {
            const u16* up = uEb + (long)lp[j] * DD + c4;
            const s16x4 v = *(const s16x4*)up;
            acc[0] += bf2f((u16)v[0]); acc[1] += bf2f((u16)v[1]);
            acc[2] += bf2f((u16)v[2]); acc[3] += bf2f((u16)v[3]);
        }
        *(f32x4*)&accl[sub * 128 + c4] = acc;
        __syncthreads();
        if (tid < 128) {
            float s = 0.f;
            #pragma unroll
            for (int q2 = 0; q2 < 8; ++q2) s += accl[q2 * 128 + tid];
            eaggp[((long)p * BG_ + bg) * DD + tid] = s;
        }
        return;
    }

    u16* Bs = (u16*)smem;                      // [64*384]
    const int bid = blockIdx.x;                // 0..511
    const int bb = bid & 7;
    const int jj = bid >> 3;
    const int ch = jj & 1;
    const int rt = jj >> 1;
    const int row0 = bb * N_ + rt * 128;

    const int wv = tid >> 6, l = tid & 63;
    const int fr = l & 15, fg = l >> 4;
    const int rowbase = row0 + wv * 32;
    const int R0 = rowbase + fr, R1 = R0 + 16;

    {
        const char* wsrc = (const char*)(WnT2 + (long)ch * 24576) + l * 16;
        char* ldst = (char*)Bs;
        #pragma unroll
        for (int i2 = 0; i2 < 12; ++i2) {
            const int off = (wv * 12 + i2) * 1024;
            __builtin_amdgcn_global_load_lds(
                (const __attribute__((address_space(1))) void*)(wsrc + off),
                (__attribute__((address_space(3))) void*)(ldst + off),
                16, 0, 0);
        }
    }

    const u16* pN0 = nodesB + (long)R0 * DD;
    const u16* pN1 = nodesB + (long)R1 * DD;
    const u16* pG0 = globB + ((long)bb * G_ + ngi[R0]) * DD;
    const u16* pG1 = globB + ((long)bb * G_ + ngi[R1]) * DD;
    short8 PN0[4], PN1[4], PG0[4], PG1[4], PA0[4], PA1[4];
    #pragma unroll
    for (int ss = 0; ss < 4; ++ss) {
        PN0[ss] = *(const short8*)(pN0 + ss * 32 + fg * 8);
        PN1[ss] = *(const short8*)(pN1 + ss * 32 + fg * 8);
        PG0[ss] = *(const short8*)(pG0 + ss * 32 + fg * 8);
        PG1[ss] = *(const short8*)(pG1 + ss * 32 + fg * 8);
    }

    {
        float ga[32];
        const int deg0 = cnt[R0];
        const int* lp0 = elist + (long)bb * E_ + (cur[R0] - deg0);
        #pragma unroll
        for (int j = 0; j < 32; ++j) ga[j] = 0.f;
        for (int i = 0; i < deg0; ++i) {
            const u16* up = uEb + (long)lp0[i] * DD + fg * 8;
            #pragma unroll
            for (int ss = 0; ss < 4; ++ss) {
                const short8 v = *(const short8*)(up + ss * 32);
                #pragma unroll
                for (int e2 = 0; e2 < 8; ++e2) ga[ss * 8 + e2] += bf2f((u16)v[e2]);
            }
        }
        #pragma unroll
        for (int ss = 0; ss < 4; ++ss) {
            short8 h;
            #pragma unroll
            for (int e2 = 0; e2 < 8; ++e2) h[e2] = (short)f2bf(ga[ss * 8 + e2]);
            PA0[ss] = h;
        }
        const int deg1 = cnt[R1];
        const int* lp1 = elist + (long)bb * E_ + (cur[R1] - deg1);
        #pragma unroll
        for (int j = 0; j < 32; ++j) ga[j] = 0.f;
        for (int i = 0; i < deg1; ++i) {
            const u16* up = uEb + (long)lp1[i] * DD + fg * 8;
            #pragma unroll
            for (int ss = 0; ss < 4; ++ss) {
                const short8 v = *(const short8*)(up + ss * 32);
                #pragma unroll
                for (int e2 = 0; e2 < 8; ++e2) ga[ss * 8 + e2] += bf2f((u16)v[e2]);
            }
        }
        #pragma unroll
        for (int ss = 0; ss < 4; ++ss) {
            short8 h;
            #pragma unroll
            for (int e2 = 0; e2 < 8; ++e2) h[e2] = (short)f2bf(ga[ss * 8 + e2]);
            PA1[ss] = h;
        }
    }

    f32x4 acc0[4], acc1[4];
    const f32x4 fz = {0.f, 0.f, 0.f, 0.f};
    #pragma unroll
    for (int i = 0; i < 4; ++i) { acc0[i] = fz; acc1[i] = fz; }

    __syncthreads();

    const char* bsp = (const char*)Bs;
    const int swr = (fr & 7) << 4;
    #pragma unroll
    for (int seg = 0; seg < 3; ++seg) {
        __builtin_amdgcn_s_setprio(1);
        #pragma unroll
        for (int ss = 0; ss < 4; ++ss) {
            const short8 a0 = (seg == 0) ? PN0[ss] : (seg == 1) ? PA0[ss] : PG0[ss];
            const short8 a1 = (seg == 0) ? PN1[ss] : (seg == 1) ? PA1[ss] : PG1[ss];
            #pragma unroll
            for (int nt = 0; nt < 4; ++nt) {
                const int addr = (nt * 16 + fr) * 768 +
                                 ((seg * 256 + ss * 64 + fg * 16) ^ swr);
                const short8 b = *(const short8*)(bsp + addr);
                acc0[nt] = __builtin_amdgcn_mfma_f32_16x16x32_bf16(b, a0, acc0[nt], 0, 0, 0);
                acc1[nt] = __builtin_amdgcn_mfma_f32_16x16x32_bf16(b, a1, acc1[nt], 0, 0, 0);
            }
        }
        __builtin_amdgcn_s_setprio(0);
    }

    const float wr = w_res[0];
    #pragma unroll
    for (int nt = 0; nt < 4; ++nt) {
        const int c = ch * 64 + nt * 16 + fg * 4;
        const float4 bv = *(const float4*)(bn + c);
        const float4 n0 = *(const float4*)(nodes + (long)R0 * DD + c);
        const float4 n1 = *(const float4*)(nodes + (long)R1 * DD + c);
        const float u00 = fmaxf(acc0[nt][0] + bv.x, 0.f);
        const float u01 = fmaxf(acc0[nt][1] + bv.y, 0.f);
        const float u02 = fmaxf(acc0[nt][2] + bv.z, 0.f);
        const float u03 = fmaxf(acc0[nt][3] + bv.w, 0.f);
        const float u10 = fmaxf(acc1[nt][0] + bv.x, 0.f);
        const float u11 = fmaxf(acc1[nt][1] + bv.y, 0.f);
        const float u12 = fmaxf(acc1[nt][2] + bv.z, 0.f);
        const float u13 = fmaxf(acc1[nt][3] + bv.w, 0.f);
        s16x4 h0, h1;
        h0[0] = (short)f2bf(u00); h0[1] = (short)f2bf(u01);
        h0[2] = (short)f2bf(u02); h0[3] = (short)f2bf(u03);
        h1[0] = (short)f2bf(u10); h1[1] = (short)f2bf(u11);
        h1[2] = (short)f2bf(u12); h1[3] = (short)f2bf(u13);
        *(s16x4*)(uNb + (long)R0 * DD + c) = h0;
        *(s16x4*)(uNb + (long)R1 * DD + c) = h1;
        float4 o0, o1;
        o0.x = n0.x + wr * u00; o0.y = n0.y + wr * u01;
        o0.z = n0.z + wr * u02; o0.w = n0.w + wr * u03;
        o1.x = n1.x + wr * u10; o1.y = n1.y + wr * u11;
        o1.z = n1.z + wr * u12; o1.w = n1.w + wr * u13;
        *(float4*)(outN + (long)R0 * DD + c) = o0;
        *(float4*)(outN + (long)R1 * DD + c) = o1;
    }
}

// -------- agg = per-(b,g) gather-sum of bf16 u rows (node aggregate) ------
__global__ __launch_bounds__(256) void agg_only(
    const int* __restrict__ gcnt, const int* __restrict__ gcur,
    const int* __restrict__ gelist, int spb, const u16* __restrict__ uB,
    float* __restrict__ aggp /* [PART][BG][DD] */) {
    __shared__ float accl[1024];
    const int bg = blockIdx.x >> 2;            // grid = BG*PART
    const int p  = blockIdx.x & 3;
    const int b = bg >> 6;
    const int tid = threadIdx.x;
    const int c4 = (tid & 31) << 2;
    const int sub = tid >> 5;                  // 0..7
    const int m = gcnt[bg];
    const int* lp = gelist + (long)b * spb + (gcur[bg] - m);
    f32x4 acc = {0.f, 0.f, 0.f, 0.f};
    for (int j = p * 8 + sub; j < m; j += 32) {
        const u16* up = uB + (long)lp[j] * DD + c4;
        const s16x4 v = *(const s16x4*)up;
        acc[0] += bf2f((u16)v[0]); acc[1] += bf2f((u16)v[1]);
        acc[2] += bf2f((u16)v[2]); acc[3] += bf2f((u16)v[3]);
    }
    *(f32x4*)&accl[sub * 128 + c4] = acc;
    __syncthreads();
    if (tid < 128) {
        float s = 0.f;
        #pragma unroll
        for (int q2 = 0; q2 < 8; ++q2) s += accl[q2 * 128 + tid];
        aggp[((long)p * BG_ + bg) * DD + tid] = s;
    }
}

// ---------------- global block: 512 rows, K=384, fp32 VALU ----------------
__global__ __launch_bounds__(128) void global_block(
    const float* __restrict__ naggp, const float* __restrict__ eaggp,
    const float* __restrict__ glob,
    const float* __restrict__ Wg, const float* __restrict__ bgb,
    const float* __restrict__ w_res, float* __restrict__ out) {
    __shared__ float gin[384];
    const int row = blockIdx.x;
    const int tid = threadIdx.x;
    float sn = 0.f, se = 0.f;
    #pragma unroll
    for (int p = 0; p < PART; ++p) {
        sn += naggp[((long)p * BG_ + row) * DD + tid];
        se += eaggp[((long)p * BG_ + row) * DD + tid];
    }
    gin[tid]       = sn;
    gin[128 + tid] = se;
    gin[256 + tid] = glob[row * DD + tid];
    __syncthreads();
    float acc = bgb[tid];
    #pragma unroll 4
    for (int k = 0; k < 384; ++k) acc += gin[k] * Wg[k * DD + tid];
    const float upd = fmaxf(acc, 0.f);
    out[OFF_GLOB + row * DD + tid] = glob[row * DD + tid] + w_res[0] * upd;
}

extern "C" void kernel_launch(void* const* d_in, const int* in_sizes, int n_in,
                              void* d_out, int out_size, void* d_ws, size_t ws_size,
                              hipStream_t stream) {
    const float* nodes     = (const float*)d_in[0];
    const float* edges     = (const float*)d_in[1];
    const int*   receivers = (const int*)d_in[2];
    const int*   senders   = (const int*)d_in[3];
    const float* glob      = (const float*)d_in[4];
    const int*   ngi       = (const int*)d_in[5];
    const int*   egi       = (const int*)d_in[6];
    const float* We        = (const float*)d_in[7];
    const float* be        = (const float*)d_in[8];
    const float* Wn        = (const float*)d_in[9];
    const float* bn        = (const float*)d_in[10];
    const float* Wg        = (const float*)d_in[11];
    const float* bg        = (const float*)d_in[12];
    const float* w_res     = (const float*)d_in[13];
    float* out = (float*)d_out;
    float* ws  = (float*)d_ws;

    float* eaggp = ws + WS_EAGGP;
    float* naggp = ws + WS_NAGGP;
    int* cnt      = (int*)(ws + WS_CNT);
    int* gcnt_e   = (int*)(ws + WS_GCNTE);
    int* gcnt_n   = (int*)(ws + WS_GCNTN);
    int* cur      = (int*)(ws + WS_CUR);
    int* gcur_e   = (int*)(ws + WS_GCURE);
    int* gcur_n   = (int*)(ws + WS_GCURN);
    int* elist    = (int*)(ws + WS_ELIST);
    int* gelist_e = (int*)(ws + WS_GELE);
    int* gelist_n = (int*)(ws + WS_GELN);
    u16* nodesB = (u16*)(ws + WS_NODB);
    u16* globB  = (u16*)(ws + WS_GLOBB);
    u16* WeT2   = (u16*)(ws + WS_WET);
    u16* WnT2   = (u16*)(ws + WS_WNT);
    u16* uEb    = (u16*)(ws + WS_UEB);
    u16* edgesB = (u16*)(ws + WS_EDGB);
    u16* uNb    = (u16*)(ws + WS_EDGB);  // reuses edgesB region (consumed)

    float* outE = out + OFF_EDGES;
    float* outN = out + OFF_NODES;

    // zero cnt + gcnt_e + gcnt_n (contiguous) before the prep+hist kernel
    hipMemsetAsync(cnt, 0, (size_t)(BN_ + 1024) * sizeof(int), stream);

    hipLaunchKernelGGL(prep_all, dim3(RE_END / 256), dim3(256), 0, stream,
                       We, Wn, WeT2, WnT2, nodes, glob, edges,
                       nodesB, globB, edgesB,
                       receivers, senders, ngi, egi, out,
                       cnt, gcnt_e, gcnt_n);
    hipLaunchKernelGGL(k_scan, dim3(8), dim3(1024), 0, stream,
                       cnt, cur, gcnt_e, gcur_e, gcnt_n, gcur_n);
    hipLaunchKernelGGL(k_fill_all, dim3(512), dim3(256), 0, stream,
                       receivers, egi, ngi, cur, elist, gcur_e, gelist_e,
                       gcur_n, gelist_n);
    hipLaunchKernelGGL(edge_mfma, dim3(2048), dim3(256), 0, stream,
                       edgesB, nodesB, globB, receivers, senders, egi,
                       WeT2, be, w_res, outE, uEb);
    hipLaunchKernelGGL(node_agge, dim3(2560), dim3(256), 0, stream,
                       nodesB, uEb, globB, ngi, cnt, cur, elist,
                       WnT2, bn, nodes, w_res, outN, uNb,
                       gcnt_e, gcur_e, gelist_e, eaggp);
    hipLaunchKernelGGL(agg_only, dim3(BG_ * PART), dim3(256), 0, stream,
                       gcnt_n, gcur_n, gelist_n, N_, uNb, naggp);
    hipLaunchKernelGGL(global_block, dim3(BG_), dim3(128), 0, stream,
                       naggp, eaggp, glob, Wg, bg, w_res, out);
}

// Round 20
// 167.786 us; speedup vs baseline: 1.3689x; 1.3689x over previous
//
#include <hip/hip_runtime.h>

// GraphNetworkLayer: B=8, N=4096, E=16384, G=64, D=128, fp32 in/out.
// Round 20: R19 config with contended-atomic fix (G12):
//  - prep_all hist tail: per-block LDS histogram (128 bins) for egi/ngi;
//    one global atomic per nonzero bin (164K contended atomics -> <=33K).
//  - k_fill_all: LDS count -> per-bin range reservation (one atomicAdd per
//    bin per block) -> scatter via LDS cursors. gcur post-state unchanged.
// All other kernels byte-identical to R19 (edge 49us validated).

#define DD 128
typedef unsigned short u16;
typedef __attribute__((ext_vector_type(8))) short short8;   // 8 bf16
typedef __attribute__((ext_vector_type(4))) short s16x4;    // 4 bf16
typedef __attribute__((ext_vector_type(4))) float f32x4;

constexpr int B_ = 8, N_ = 4096, E_ = 16384, G_ = 64;
constexpr int NODES_SZ = B_ * N_ * DD;   // 4,194,304
constexpr int EDGES_SZ = B_ * E_ * DD;   // 16,777,216
constexpr int BE_ = B_ * E_;             // 131,072
constexpr int BN_ = B_ * N_;             // 32,768
constexpr int BG_ = B_ * G_;             // 512
constexpr int GLOB_SZ = BG_ * DD;        // 65,536
constexpr int PART = 4;

constexpr int OFF_NODES = 0;
constexpr int OFF_EDGES = OFF_NODES + NODES_SZ;
constexpr int OFF_RECV  = OFF_EDGES + EDGES_SZ;
constexpr int OFF_SEND  = OFF_RECV + BE_;
constexpr int OFF_GLOB  = OFF_SEND + BE_;
constexpr int OFF_NGI   = OFF_GLOB + GLOB_SZ;
constexpr int OFF_EGI   = OFF_NGI + BN_;

// prep_all region boundaries (thread indices)
constexpr int NT_CH   = NODES_SZ / 8;                // 524288 nodes chunks
constexpr int GL_CH   = GLOB_SZ / 8;                 // 8192 glob chunks
constexpr int RW_END  = 114688;                      // weights (1/thread)
constexpr int RB_END  = RW_END + (NT_CH + GL_CH) / 4;   // 247808
constexpr int RC_END  = RB_END + (EDGES_SZ / 8) / 4;    // 772096
constexpr int RD_END  = RC_END + (3 * BE_ + BN_) / 4;   // 878592
constexpr int RE_END  = RD_END + BE_;                   // 1009664
// grid = RE_END / 256 = 3944 (exact); all region bounds 256-aligned

// ws layout (float-element offsets) — R15/R18 layout
constexpr int WS_EAGGP = 0;                          // [PART][BG][DD] f32
constexpr int WS_NAGGP = WS_EAGGP + PART * GLOB_SZ;
constexpr int WS_CNT   = WS_NAGGP + PART * GLOB_SZ;  // int [B*N] (memset 0)
constexpr int WS_GCNTE = WS_CNT + BN_;               // int [512] (memset 0)
constexpr int WS_GCNTN = WS_GCNTE + 512;             // int [512] (memset 0)
constexpr int WS_CUR   = WS_GCNTN + 512;             // int [B*N]
constexpr int WS_GCURE = WS_CUR + BN_;               // int [512]
constexpr int WS_GCURN = WS_GCURE + 512;             // int [512]
constexpr int WS_ELIST = WS_GCURN + 512;             // int [B*E]
constexpr int WS_GELE  = WS_ELIST + BE_;             // int [B*E]
constexpr int WS_GELN  = WS_GELE + BE_;              // int [B*N]
constexpr int WS_ADJB  = WS_GELN + BN_;              // (unused)
constexpr int WS_NODB  = WS_ADJB + (BN_ * DD) / 2;   // u16 [B,N,D]
constexpr int WS_GLOBB = WS_NODB + (BN_ * DD) / 2;   // u16 [B,G,D]
constexpr int WS_WET   = WS_GLOBB + GLOB_SZ / 2;     // u16 [128*512] swz image
constexpr int WS_WNT   = WS_WET + 32768;             // u16 [128*384] swz image
constexpr int WS_UEB   = WS_WNT + 24576;             // u16 [B,E,D] bf16 u_e
constexpr int WS_EDGB  = WS_UEB + (BE_ * DD) / 2;    // u16 [B,E,D] edgesB; uNb aliases

__device__ inline u16 f2bf(float f) {
    union { float f; unsigned u; } v; v.f = f;
    return (u16)((v.u + 0x7fffu + ((v.u >> 16) & 1u)) >> 16);
}
__device__ inline float bf2f(u16 h) {
    union { unsigned u; float f; } v; v.u = ((unsigned)h) << 16; return v.f;
}
__device__ inline short8 pack8(float4 a, float4 b) {
    short8 r;
    r[0] = (short)f2bf(a.x); r[1] = (short)f2bf(a.y);
    r[2] = (short)f2bf(a.z); r[3] = (short)f2bf(a.w);
    r[4] = (short)f2bf(b.x); r[5] = (short)f2bf(b.y);
    r[6] = (short)f2bf(b.z); r[7] = (short)f2bf(b.w);
    return r;
}

// -------- fused prep + LDS-aggregated histogram tail --------
__global__ __launch_bounds__(256) void prep_all(
    const float* __restrict__ We, const float* __restrict__ Wn,
    u16* __restrict__ WeT2, u16* __restrict__ WnT2,
    const float* __restrict__ nodes, const float* __restrict__ glob,
    const float* __restrict__ edges,
    u16* __restrict__ nodesB, u16* __restrict__ globB, u16* __restrict__ edgesB,
    const int* __restrict__ recv, const int* __restrict__ send,
    const int* __restrict__ ngi, const int* __restrict__ egi,
    float* __restrict__ out,
    int* __restrict__ cnt, int* __restrict__ gcnt_e, int* __restrict__ gcnt_n) {
    __shared__ int lh[128];
    const int tid = threadIdx.x;
    const int i = blockIdx.x * 256 + tid;
    if (i < RW_END) {
        // weights -> pre-swizzled bf16 images (scattered gather, 1/thread)
        if (i < 65536) {
            const int ch = i >> 15;
            const int r = i & 32767;
            const int row = r >> 9;
            const int inb = (r << 1) & 1023;
            const int kb = inb ^ ((row & 7) << 4);
            WeT2[i] = f2bf(We[(kb >> 1) * DD + ch * 64 + row]);
        } else {
            const int q = i - 65536;
            const int ch = q / 24576;
            const int r = q % 24576;
            const int row = r / 384;
            const int inb = (r % 384) << 1;
            const int kb = inb ^ ((row & 7) << 4);
            WnT2[q] = f2bf(Wn[(kb >> 1) * DD + ch * 64 + row]);
        }
    } else if (i < RB_END) {
        const long c0 = ((long)(i - RW_END)) << 2;
        if (c0 < NT_CH) {
            float4 a[4], b[4];
            #pragma unroll
            for (int t = 0; t < 4; ++t) {
                a[t] = *(const float4*)(nodes + (c0 + t) * 8);
                b[t] = *(const float4*)(nodes + (c0 + t) * 8 + 4);
            }
            #pragma unroll
            for (int t = 0; t < 4; ++t)
                *(short8*)(nodesB + (c0 + t) * 8) = pack8(a[t], b[t]);
        } else {
            const long c2 = c0 - NT_CH;
            float4 a[4], b[4];
            #pragma unroll
            for (int t = 0; t < 4; ++t) {
                a[t] = *(const float4*)(glob + (c2 + t) * 8);
                b[t] = *(const float4*)(glob + (c2 + t) * 8 + 4);
            }
            #pragma unroll
            for (int t = 0; t < 4; ++t)
                *(short8*)(globB + (c2 + t) * 8) = pack8(a[t], b[t]);
        }
    } else if (i < RC_END) {
        const long c0 = ((long)(i - RB_END)) << 2;
        float4 a[4], b[4];
        #pragma unroll
        for (int t = 0; t < 4; ++t) {
            a[t] = *(const float4*)(edges + (c0 + t) * 8);
            b[t] = *(const float4*)(edges + (c0 + t) * 8 + 4);
        }
        #pragma unroll
        for (int t = 0; t < 4; ++t)
            *(short8*)(edgesB + (c0 + t) * 8) = pack8(a[t], b[t]);
    } else if (i < RD_END) {
        const int k = (i - RC_END) << 2;
        const int* src;
        long dst;
        int loc;
        if (k < BE_)                 { src = recv; loc = k;               dst = OFF_RECV + loc; }
        else if (k < 2 * BE_)        { src = send; loc = k - BE_;         dst = OFF_SEND + loc; }
        else if (k < 2 * BE_ + BN_)  { src = ngi;  loc = k - 2 * BE_;     dst = OFF_NGI + loc; }
        else                         { src = egi;  loc = k - 2 * BE_ - BN_; dst = OFF_EGI + loc; }
        const int4 v = *(const int4*)(src + loc);
        float4 o;
        o.x = (float)v.x; o.y = (float)v.y; o.z = (float)v.z; o.w = (float)v.w;
        *(float4*)(out + dst) = o;
    } else {
        // histogram tail: LDS-aggregated gcnt, direct cnt (low contention).
        // Blocks never straddle batches (256 | 16384 and 256 | 4096).
        const int k3 = i - RD_END;                  // < BE_
        const int b = k3 >> 14;
        const int k30 = blockIdx.x * 256 - RD_END;  // block's first k3
        const bool isnb = (k30 < BN_);
        if (tid < 128) lh[tid] = 0;
        __syncthreads();
        atomicAdd(&cnt[b * N_ + recv[k3]], 1);
        atomicAdd(&lh[egi[k3]], 1);
        if (isnb) atomicAdd(&lh[64 + ngi[k3]], 1);
        __syncthreads();
        if (tid < 64) {
            const int v = lh[tid];
            if (v) atomicAdd(&gcnt_e[b * G_ + tid], v);
        } else if (tid < 128 && isnb) {
            const int v = lh[tid];
            if (v) atomicAdd(&gcnt_n[(k30 >> 12) * G_ + (tid - 64)], v);
        }
    }
}

__global__ __launch_bounds__(1024) void k_scan(
    const int* __restrict__ cnt, int* __restrict__ cur,
    const int* __restrict__ gcnt_e, int* __restrict__ gcur_e,
    const int* __restrict__ gcnt_n, int* __restrict__ gcur_n) {
    __shared__ int s[1024];
    const int b = blockIdx.x;
    const int t = threadIdx.x;
    const int base = b * N_;
    int c[4];
    int sum = 0;
    #pragma unroll
    for (int i = 0; i < 4; ++i) { c[i] = cnt[base + 4 * t + i]; sum += c[i]; }
    s[t] = sum;
    __syncthreads();
    for (int off = 1; off < 1024; off <<= 1) {
        int v = s[t];
        if (t >= off) v += s[t - off];
        __syncthreads();
        s[t] = v;
        __syncthreads();
    }
    int eb = s[t] - sum;
    #pragma unroll
    for (int i = 0; i < 4; ++i) { cur[base + 4 * t + i] = eb; eb += c[i]; }
    __syncthreads();
    int gv = 0;
    if (t < G_) { gv = gcnt_e[b * G_ + t]; s[t] = gv; }
    __syncthreads();
    for (int off = 1; off < G_; off <<= 1) {
        int v = 0;
        if (t < G_) { v = s[t]; if (t >= off) v += s[t - off]; }
        __syncthreads();
        if (t < G_) s[t] = v;
        __syncthreads();
    }
    if (t < G_) gcur_e[b * G_ + t] = s[t] - gv;
    __syncthreads();
    if (t < G_) { gv = gcnt_n[b * G_ + t]; s[t] = gv; }
    __syncthreads();
    for (int off = 1; off < G_; off <<= 1) {
        int v = 0;
        if (t < G_) { v = s[t]; if (t >= off) v += s[t - off]; }
        __syncthreads();
        if (t < G_) s[t] = v;
        __syncthreads();
    }
    if (t < G_) gcur_n[b * G_ + t] = s[t] - gv;
}

// -------- fill: LDS range-reservation for gelist (contended bins) ---------
__global__ __launch_bounds__(256) void k_fill_all(
    const int* __restrict__ recv, const int* __restrict__ egi,
    const int* __restrict__ ngi,
    int* __restrict__ cur, int* __restrict__ elist,
    int* __restrict__ gcur_e, int* __restrict__ gelist_e,
    int* __restrict__ gcur_n, int* __restrict__ gelist_n) {
    __shared__ int lcnt[128], lbase[128];
    const int tid = threadIdx.x;
    const int i = blockIdx.x * 256 + tid;
    const int b = i >> 14;
    const int i0 = blockIdx.x * 256;
    const bool isnb = (i0 < BN_);
    if (tid < 128) lcnt[tid] = 0;
    __syncthreads();
    // receiver elist: direct (4096 bins/batch, low contention)
    const int s1 = atomicAdd(&cur[b * N_ + recv[i]], 1);
    elist[b * E_ + s1] = i;
    // gelist_e / gelist_n: block-aggregated reservation
    const int ge = egi[i];
    const int loc_e = atomicAdd(&lcnt[ge], 1);
    int gn = 0, loc_n = 0;
    if (isnb) { gn = ngi[i]; loc_n = atomicAdd(&lcnt[64 + gn], 1); }
    __syncthreads();
    if (tid < 64) {
        const int v = lcnt[tid];
        if (v) lbase[tid] = atomicAdd(&gcur_e[b * G_ + tid], v);
    } else if (tid < 128 && isnb) {
        const int v = lcnt[tid];
        if (v) lbase[tid] = atomicAdd(&gcur_n[(i0 >> 12) * G_ + (tid - 64)], v);
    }
    __syncthreads();
    gelist_e[(long)b * E_ + lbase[ge] + loc_e] = i;
    if (isnb) gelist_n[(long)(i0 >> 12) * N_ + lbase[64 + gn] + loc_n] = i;
}

// -------- edge GEMM: UNCHANGED (R15: 128x64, M-rep 2, K-step 64, dbuf) ----
__global__ __launch_bounds__(256, 3) void edge_mfma(
    const u16* __restrict__ edgesB, const u16* __restrict__ nodesB,
    const u16* __restrict__ globB,
    const int* __restrict__ receivers, const int* __restrict__ senders,
    const int* __restrict__ egi,
    const u16* __restrict__ WeT2, const float* __restrict__ be,
    const float* __restrict__ w_res,
    float* __restrict__ outE, u16* __restrict__ uEb) {
    __shared__ u16 As[2][128 * 64];            // 2 x 16 KB (rows x 128B)
    __shared__ u16 Bs[2][64 * 64];             // 2 x 8 KB  (cols x 128B)
    const int tid = threadIdx.x;
    const int bid = blockIdx.x;                // 2048
    const int bb = bid & 7;                    // batch = XCD
    const int q = bid >> 3;                    // 0..255
    const int ch = q & 1;
    const int rt = q >> 1;                     // 0..127
    const int row0 = bb * E_ + rt * 128;

    const int wv = tid >> 6, l = tid & 63;
    const int fr = l & 15, fg = l >> 4;
    const int lrow0 = wv * 32 + fr;            // 0..127
    const int R0 = row0 + lrow0, R1 = R0 + 16;

    const char* img = (const char*)(WeT2 + (long)ch * 32768);
    const int swz = (fr & 7) << 4;

    auto stage = [&](int kk, int buf) {
        const int seg = kk >> 1, half = kk & 1;
        #pragma unroll
        for (int i = 0; i < 4; ++i) {          // A: 1024 chunks of 16B
            const int gci = i * 256 + tid;
            const int r = gci >> 3, j = gci & 7;
            const int gr = row0 + r;
            const u16* rp;
            if (seg == 0)      rp = edgesB + (long)gr * DD;
            else if (seg == 1) rp = nodesB + ((long)bb * N_ + senders[gr]) * DD;
            else if (seg == 2) rp = nodesB + ((long)bb * N_ + receivers[gr]) * DD;
            else               rp = globB + ((long)bb * G_ + egi[gr]) * DD;
            const char* src = (const char*)rp + half * 128 +
                              ((j * 16) ^ ((r & 7) << 4));
            char* dst = (char*)As[buf] + r * 128 + j * 16;
            __builtin_amdgcn_global_load_lds(
                (const __attribute__((address_space(1))) void*)src,
                (__attribute__((address_space(3))) void*)dst, 16, 0, 0);
        }
        #pragma unroll
        for (int i = 0; i < 2; ++i) {          // B: 512 chunks of 16B
            const int gci = i * 256 + tid;
            const int col = gci >> 3, j = gci & 7;
            const char* src = img + (long)col * 1024 + kk * 128 + j * 16;
            char* dst = (char*)Bs[buf] + col * 128 + j * 16;
            __builtin_amdgcn_global_load_lds(
                (const __attribute__((address_space(1))) void*)src,
                (__attribute__((address_space(3))) void*)dst, 16, 0, 0);
        }
    };

    f32x4 acc0[4], acc1[4];
    const f32x4 fz = {0.f, 0.f, 0.f, 0.f};
    #pragma unroll
    for (int i = 0; i < 4; ++i) { acc0[i] = fz; acc1[i] = fz; }
    s16x4 eres0[4], eres1[4];

    stage(0, 0);
    __syncthreads();

    #pragma unroll
    for (int kk = 0; kk < 8; ++kk) {
        const int buf = kk & 1;
        if (kk < 7) {
            stage(kk + 1, buf ^ 1);
            __builtin_amdgcn_sched_barrier(0);
        }
        __builtin_amdgcn_s_setprio(1);
        #pragma unroll
        for (int ss = 0; ss < 2; ++ss) {
            const int ko = (ss * 64 + fg * 16) ^ swz;
            const short8 a0 = *(const short8*)((char*)As[buf] + lrow0 * 128 + ko);
            const short8 a1 = *(const short8*)((char*)As[buf] + (lrow0 + 16) * 128 + ko);
            #pragma unroll
            for (int nt = 0; nt < 4; ++nt) {
                const short8 b = *(const short8*)((char*)Bs[buf] + (nt * 16 + fr) * 128 + ko);
                acc0[nt] = __builtin_amdgcn_mfma_f32_16x16x32_bf16(b, a0, acc0[nt], 0, 0, 0);
                acc1[nt] = __builtin_amdgcn_mfma_f32_16x16x32_bf16(b, a1, acc1[nt], 0, 0, 0);
            }
        }
        __builtin_amdgcn_s_setprio(0);
        if (kk == ch) {
            #pragma unroll
            for (int nt = 0; nt < 4; ++nt) {
                const int jb = (nt * 32 + fg * 8) ^ swz;
                eres0[nt] = *(const s16x4*)((char*)As[buf] + lrow0 * 128 + jb);
                eres1[nt] = *(const s16x4*)((char*)As[buf] + (lrow0 + 16) * 128 + jb);
            }
        }
        if (kk < 7) __syncthreads();
    }

    const float wr = w_res[0];
    #pragma unroll
    for (int nt = 0; nt < 4; ++nt) {
        const int c = ch * 64 + nt * 16 + fg * 4;
        const float4 bv = *(const float4*)(be + c);
        const float u00 = fmaxf(acc0[nt][0] + bv.x, 0.f);
        const float u01 = fmaxf(acc0[nt][1] + bv.y, 0.f);
        const float u02 = fmaxf(acc0[nt][2] + bv.z, 0.f);
        const float u03 = fmaxf(acc0[nt][3] + bv.w, 0.f);
        const float u10 = fmaxf(acc1[nt][0] + bv.x, 0.f);
        const float u11 = fmaxf(acc1[nt][1] + bv.y, 0.f);
        const float u12 = fmaxf(acc1[nt][2] + bv.z, 0.f);
        const float u13 = fmaxf(acc1[nt][3] + bv.w, 0.f);
        s16x4 h0, h1;
        h0[0] = (short)f2bf(u00); h0[1] = (short)f2bf(u01);
        h0[2] = (short)f2bf(u02); h0[3] = (short)f2bf(u03);
        h1[0] = (short)f2bf(u10); h1[1] = (short)f2bf(u11);
        h1[2] = (short)f2bf(u12); h1[3] = (short)f2bf(u13);
        *(s16x4*)(uEb + (long)R0 * DD + c) = h0;
        *(s16x4*)(uEb + (long)R1 * DD + c) = h1;
        float4 o0, o1;
        o0.x = bf2f((u16)eres0[nt][0]) + wr * u00;
        o0.y = bf2f((u16)eres0[nt][1]) + wr * u01;
        o0.z = bf2f((u16)eres0[nt][2]) + wr * u02;
        o0.w = bf2f((u16)eres0[nt][3]) + wr * u03;
        o1.x = bf2f((u16)eres1[nt][0]) + wr * u10;
        o1.y = bf2f((u16)eres1[nt][1]) + wr * u11;
        o1.z = bf2f((u16)eres1[nt][2]) + wr * u12;
        o1.w = bf2f((u16)eres1[nt][3]) + wr * u13;
        *(float4*)(outE + (long)R0 * DD + c) = o0;
        *(float4*)(outE + (long)R1 * DD + c) = o1;
    }
}

// -------- merged: node GEMM (blocks 0..511) + eagg gather (512..2559) -----
__global__ __launch_bounds__(256, 3) void node_agge(
    const u16* __restrict__ nodesB, const u16* __restrict__ uEb,
    const u16* __restrict__ globB, const int* __restrict__ ngi,
    const int* __restrict__ cnt, const int* __restrict__ cur,
    const int* __restrict__ elist,
    const u16* __restrict__ WnT2, const float* __restrict__ bn,
    const float* __restrict__ nodes, const float* __restrict__ w_res,
    float* __restrict__ outN, u16* __restrict__ uNb,
    const int* __restrict__ gcnt_e, const int* __restrict__ gcur_e,
    const int* __restrict__ gelist_e, float* __restrict__ eaggp) {
    __shared__ char smem[64 * 384 * 2];        // 48 KB (union)
    const int tid = threadIdx.x;

    if (blockIdx.x >= 512) {
        float* accl = (float*)smem;
        const int abid = blockIdx.x - 512;     // 0..2047
        const int bg = abid >> 2;
        const int p  = abid & 3;
        const int b = bg >> 6;
        const int c4 = (tid & 31) << 2;
        const int sub = tid >> 5;
        const int m = gcnt_e[bg];
        const int* lp = gelist_e + (long)b * E_ + (gcur_e[bg] - m);
        f32x4 acc = {0.f, 0.f, 0.f, 0.f};
        for (int j = p * 8 + sub; j < m; j += 32) {
            const u16* up = uEb + (long)lp[j] * DD + c4;
            const s16x4 v = *(const s16x4*)up;
            acc[0] += bf2f((u16)v[0]); acc[1] += bf2f((u16)v[1]);
            acc[2] += bf2f((u16)v[2]); acc[3] += bf2f((u16)v[3]);
        }
        *(f32x4*)&accl[sub * 128 + c4] = acc;
        __syncthreads();
        if (tid < 128) {
            float s = 0.f;
            #pragma unroll
            for (int q2 = 0; q2 < 8; ++q2) s += accl[q2 * 128 + tid];
            eaggp[((long)p * BG_ + bg) * DD + tid] = s;
        }
        return;
    }

    u16* Bs = (u16*)smem;                      // [64*384]
    const int bid = blockIdx.x;                // 0..511
    const int bb = bid & 7;
    const int jj = bid >> 3;
    const int ch = jj & 1;
    const int rt = jj >> 1;
    const int row0 = bb * N_ + rt * 128;

    const int wv = tid >> 6, l = tid & 63;
    const int fr = l & 15, fg = l >> 4;
    const int rowbase = row0 + wv * 32;
    const int R0 = rowbase + fr, R1 = R0 + 16;

    {
        const char* wsrc = (const char*)(WnT2 + (long)ch * 24576) + l * 16;
        char* ldst = (char*)Bs;
        #pragma unroll
        for (int i2 = 0; i2 < 12; ++i2) {
            const int off = (wv * 12 + i2) * 1024;
            __builtin_amdgcn_global_load_lds(
                (const __attribute__((address_space(1))) void*)(wsrc + off),
                (__attribute__((address_space(3))) void*)(ldst + off),
                16, 0, 0);
        }
    }

    const u16* pN0 = nodesB + (long)R0 * DD;
    const u16* pN1 = nodesB + (long)R1 * DD;
    const u16* pG0 = globB + ((long)bb * G_ + ngi[R0]) * DD;
    const u16* pG1 = globB + ((long)bb * G_ + ngi[R1]) * DD;
    short8 PN0[4], PN1[4], PG0[4], PG1[4], PA0[4], PA1[4];
    #pragma unroll
    for (int ss = 0; ss < 4; ++ss) {
        PN0[ss] = *(const short8*)(pN0 + ss * 32 + fg * 8);
        PN1[ss] = *(const short8*)(pN1 + ss * 32 + fg * 8);
        PG0[ss] = *(const short8*)(pG0 + ss * 32 + fg * 8);
        PG1[ss] = *(const short8*)(pG1 + ss * 32 + fg * 8);
    }

    {
        float ga[32];
        const int deg0 = cnt[R0];
        const int* lp0 = elist + (long)bb * E_ + (cur[R0] - deg0);
        #pragma unroll
        for (int j = 0; j < 32; ++j) ga[j] = 0.f;
        for (int i = 0; i < deg0; ++i) {
            const u16* up = uEb + (long)lp0[i] * DD + fg * 8;
            #pragma unroll
            for (int ss = 0; ss < 4; ++ss) {
                const short8 v = *(const short8*)(up + ss * 32);
                #pragma unroll
                for (int e2 = 0; e2 < 8; ++e2) ga[ss * 8 + e2] += bf2f((u16)v[e2]);
            }
        }
        #pragma unroll
        for (int ss = 0; ss < 4; ++ss) {
            short8 h;
            #pragma unroll
            for (int e2 = 0; e2 < 8; ++e2) h[e2] = (short)f2bf(ga[ss * 8 + e2]);
            PA0[ss] = h;
        }
        const int deg1 = cnt[R1];
        const int* lp1 = elist + (long)bb * E_ + (cur[R1] - deg1);
        #pragma unroll
        for (int j = 0; j < 32; ++j) ga[j] = 0.f;
        for (int i = 0; i < deg1; ++i) {
            const u16* up = uEb + (long)lp1[i] * DD + fg * 8;
            #pragma unroll
            for (int ss = 0; ss < 4; ++ss) {
                const short8 v = *(const short8*)(up + ss * 32);
                #pragma unroll
                for (int e2 = 0; e2 < 8; ++e2) ga[ss * 8 + e2] += bf2f((u16)v[e2]);
            }
        }
        #pragma unroll
        for (int ss = 0; ss < 4; ++ss) {
            short8 h;
            #pragma unroll
            for (int e2 = 0; e2 < 8; ++e2) h[e2] = (short)f2bf(ga[ss * 8 + e2]);
            PA1[ss] = h;
        }
    }

    f32x4 acc0[4], acc1[4];
    const f32x4 fz = {0.f, 0.f, 0.f, 0.f};
    #pragma unroll
    for (int i = 0; i < 4; ++i) { acc0[i] = fz; acc1[i] = fz; }

    __syncthreads();

    const char* bsp = (const char*)Bs;
    const int swr = (fr & 7) << 4;
    #pragma unroll
    for (int seg = 0; seg < 3; ++seg) {
        __builtin_amdgcn_s_setprio(1);
        #pragma unroll
        for (int ss = 0; ss < 4; ++ss) {
            const short8 a0 = (seg == 0) ? PN0[ss] : (seg == 1) ? PA0[ss] : PG0[ss];
            const short8 a1 = (seg == 0) ? PN1[ss] : (seg == 1) ? PA1[ss] : PG1[ss];
            #pragma unroll
            for (int nt = 0; nt < 4; ++nt) {
                const int addr = (nt * 16 + fr) * 768 +
                                 ((seg * 256 + ss * 64 + fg * 16) ^ swr);
                const short8 b = *(const short8*)(bsp + addr);
                acc0[nt] = __builtin_amdgcn_mfma_f32_16x16x32_bf16(b, a0, acc0[nt], 0, 0, 0);
                acc1[nt] = __builtin_amdgcn_mfma_f32_16x16x32_bf16(b, a1, acc1[nt], 0, 0, 0);
            }
        }
        __builtin_amdgcn_s_setprio(0);
    }

    const float wr = w_res[0];
    #pragma unroll
    for (int nt = 0; nt < 4; ++nt) {
        const int c = ch * 64 + nt * 16 + fg * 4;
        const float4 bv = *(const float4*)(bn + c);
        const float4 n0 = *(const float4*)(nodes + (long)R0 * DD + c);
        const float4 n1 = *(const float4*)(nodes + (long)R1 * DD + c);
        const float u00 = fmaxf(acc0[nt][0] + bv.x, 0.f);
        const float u01 = fmaxf(acc0[nt][1] + bv.y, 0.f);
        const float u02 = fmaxf(acc0[nt][2] + bv.z, 0.f);
        const float u03 = fmaxf(acc0[nt][3] + bv.w, 0.f);
        const float u10 = fmaxf(acc1[nt][0] + bv.x, 0.f);
        const float u11 = fmaxf(acc1[nt][1] + bv.y, 0.f);
        const float u12 = fmaxf(acc1[nt][2] + bv.z, 0.f);
        const float u13 = fmaxf(acc1[nt][3] + bv.w, 0.f);
        s16x4 h0, h1;
        h0[0] = (short)f2bf(u00); h0[1] = (short)f2bf(u01);
        h0[2] = (short)f2bf(u02); h0[3] = (short)f2bf(u03);
        h1[0] = (short)f2bf(u10); h1[1] = (short)f2bf(u11);
        h1[2] = (short)f2bf(u12); h1[3] = (short)f2bf(u13);
        *(s16x4*)(uNb + (long)R0 * DD + c) = h0;
        *(s16x4*)(uNb + (long)R1 * DD + c) = h1;
        float4 o0, o1;
        o0.x = n0.x + wr * u00; o0.y = n0.y + wr * u01;
        o0.z = n0.z + wr * u02; o0.w = n0.w + wr * u03;
        o1.x = n1.x + wr * u10; o1.y = n1.y + wr * u11;
        o1.z = n1.z + wr * u12; o1.w = n1.w + wr * u13;
        *(float4*)(outN + (long)R0 * DD + c) = o0;
        *(float4*)(outN + (long)R1 * DD + c) = o1;
    }
}

// -------- agg = per-(b,g) gather-sum of bf16 u rows (node aggregate) ------
__global__ __launch_bounds__(256) void agg_only(
    const int* __restrict__ gcnt, const int* __restrict__ gcur,
    const int* __restrict__ gelist, int spb, const u16* __restrict__ uB,
    float* __restrict__ aggp /* [PART][BG][DD] */) {
    __shared__ float accl[1024];
    const int bg = blockIdx.x >> 2;            // grid = BG*PART
    const int p  = blockIdx.x & 3;
    const int b = bg >> 6;
    const int tid = threadIdx.x;
    const int c4 = (tid & 31) << 2;
    const int sub = tid >> 5;                  // 0..7
    const int m = gcnt[bg];
    const int* lp = gelist + (long)b * spb + (gcur[bg] - m);
    f32x4 acc = {0.f, 0.f, 0.f, 0.f};
    for (int j = p * 8 + sub; j < m; j += 32) {
        const u16* up = uB + (long)lp[j] * DD + c4;
        const s16x4 v = *(const s16x4*)up;
        acc[0] += bf2f((u16)v[0]); acc[1] += bf2f((u16)v[1]);
        acc[2] += bf2f((u16)v[2]); acc[3] += bf2f((u16)v[3]);
    }
    *(f32x4*)&accl[sub * 128 + c4] = acc;
    __syncthreads();
    if (tid < 128) {
        float s = 0.f;
        #pragma unroll
        for (int q2 = 0; q2 < 8; ++q2) s += accl[q2 * 128 + tid];
        aggp[((long)p * BG_ + bg) * DD + tid] = s;
    }
}

// ---------------- global block: 512 rows, K=384, fp32 VALU ----------------
__global__ __launch_bounds__(128) void global_block(
    const float* __restrict__ naggp, const float* __restrict__ eaggp,
    const float* __restrict__ glob,
    const float* __restrict__ Wg, const float* __restrict__ bgb,
    const float* __restrict__ w_res, float* __restrict__ out) {
    __shared__ float gin[384];
    const int row = blockIdx.x;
    const int tid = threadIdx.x;
    float sn = 0.f, se = 0.f;
    #pragma unroll
    for (int p = 0; p < PART; ++p) {
        sn += naggp[((long)p * BG_ + row) * DD + tid];
        se += eaggp[((long)p * BG_ + row) * DD + tid];
    }
    gin[tid]       = sn;
    gin[128 + tid] = se;
    gin[256 + tid] = glob[row * DD + tid];
    __syncthreads();
    float acc = bgb[tid];
    #pragma unroll 4
    for (int k = 0; k < 384; ++k) acc += gin[k] * Wg[k * DD + tid];
    const float upd = fmaxf(acc, 0.f);
    out[OFF_GLOB + row * DD + tid] = glob[row * DD + tid] + w_res[0] * upd;
}

extern "C" void kernel_launch(void* const* d_in, const int* in_sizes, int n_in,
                              void* d_out, int out_size, void* d_ws, size_t ws_size,
                              hipStream_t stream) {
    const float* nodes     = (const float*)d_in[0];
    const float* edges     = (const float*)d_in[1];
    const int*   receivers = (const int*)d_in[2];
    const int*   senders   = (const int*)d_in[3];
    const float* glob      = (const float*)d_in[4];
    const int*   ngi       = (const int*)d_in[5];
    const int*   egi       = (const int*)d_in[6];
    const float* We        = (const float*)d_in[7];
    const float* be        = (const float*)d_in[8];
    const float* Wn        = (const float*)d_in[9];
    const float* bn        = (const float*)d_in[10];
    const float* Wg        = (const float*)d_in[11];
    const float* bg        = (const float*)d_in[12];
    const float* w_res     = (const float*)d_in[13];
    float* out = (float*)d_out;
    float* ws  = (float*)d_ws;

    float* eaggp = ws + WS_EAGGP;
    float* naggp = ws + WS_NAGGP;
    int* cnt      = (int*)(ws + WS_CNT);
    int* gcnt_e   = (int*)(ws + WS_GCNTE);
    int* gcnt_n   = (int*)(ws + WS_GCNTN);
    int* cur      = (int*)(ws + WS_CUR);
    int* gcur_e   = (int*)(ws + WS_GCURE);
    int* gcur_n   = (int*)(ws + WS_GCURN);
    int* elist    = (int*)(ws + WS_ELIST);
    int* gelist_e = (int*)(ws + WS_GELE);
    int* gelist_n = (int*)(ws + WS_GELN);
    u16* nodesB = (u16*)(ws + WS_NODB);
    u16* globB  = (u16*)(ws + WS_GLOBB);
    u16* WeT2   = (u16*)(ws + WS_WET);
    u16* WnT2   = (u16*)(ws + WS_WNT);
    u16* uEb    = (u16*)(ws + WS_UEB);
    u16* edgesB = (u16*)(ws + WS_EDGB);
    u16* uNb    = (u16*)(ws + WS_EDGB);  // reuses edgesB region (consumed)

    float* outE = out + OFF_EDGES;
    float* outN = out + OFF_NODES;

    // zero cnt + gcnt_e + gcnt_n (contiguous) before the prep+hist kernel
    hipMemsetAsync(cnt, 0, (size_t)(BN_ + 1024) * sizeof(int), stream);

    hipLaunchKernelGGL(prep_all, dim3(RE_END / 256), dim3(256), 0, stream,
                       We, Wn, WeT2, WnT2, nodes, glob, edges,
                       nodesB, globB, edgesB,
                       receivers, senders, ngi, egi, out,
                       cnt, gcnt_e, gcnt_n);
    hipLaunchKernelGGL(k_scan, dim3(8), dim3(1024), 0, stream,
                       cnt, cur, gcnt_e, gcur_e, gcnt_n, gcur_n);
    hipLaunchKernelGGL(k_fill_all, dim3(512), dim3(256), 0, stream,
                       receivers, egi, ngi, cur, elist, gcur_e, gelist_e,
                       gcur_n, gelist_n);
    hipLaunchKernelGGL(edge_mfma, dim3(2048), dim3(256), 0, stream,
                       edgesB, nodesB, globB, receivers, senders, egi,
                       WeT2, be, w_res, outE, uEb);
    hipLaunchKernelGGL(node_agge, dim3(2560), dim3(256), 0, stream,
                       nodesB, uEb, globB, ngi, cnt, cur, elist,
                       WnT2, bn, nodes, w_res, outN, uNb,
                       gcnt_e, gcur_e, gelist_e, eaggp);
    hipLaunchKernelGGL(agg_only, dim3(BG_ * PART), dim3(256), 0, stream,
                       gcnt_n, gcur_n, gelist_n, N_, uNb, naggp);
    hipLaunchKernelGGL(global_block, dim3(BG_), dim3(128), 0, stream,
                       naggp, eaggp, glob, Wg, bg, w_res, out);
}

// Round 21
// 167.475 us; speedup vs baseline: 1.3714x; 1.0019x over previous
//
#include <hip/hip_runtime.h>

// GraphNetworkLayer: B=8, N=4096, E=16384, G=64, D=128, fp32 in/out.
// Round 21: R20 config (167.8us) with ONE delta — edge_mfma K-loop uses
// counted vmcnt (T3/T4): raw s_barrier + "s_waitcnt vmcnt(6)" at step top
// (waits only stage(kk); stage(kk+1)'s 6 loads fly across both barriers),
// replacing the draining __syncthreads() (waited on the just-issued
// prefetch every step). Two raw barriers/step keep cross-wave LDS ordering.
// All other kernels byte-identical to R20.

#define DD 128
typedef unsigned short u16;
typedef __attribute__((ext_vector_type(8))) short short8;   // 8 bf16
typedef __attribute__((ext_vector_type(4))) short s16x4;    // 4 bf16
typedef __attribute__((ext_vector_type(4))) float f32x4;

constexpr int B_ = 8, N_ = 4096, E_ = 16384, G_ = 64;
constexpr int NODES_SZ = B_ * N_ * DD;   // 4,194,304
constexpr int EDGES_SZ = B_ * E_ * DD;   // 16,777,216
constexpr int BE_ = B_ * E_;             // 131,072
constexpr int BN_ = B_ * N_;             // 32,768
constexpr int BG_ = B_ * G_;             // 512
constexpr int GLOB_SZ = BG_ * DD;        // 65,536
constexpr int PART = 4;

constexpr int OFF_NODES = 0;
constexpr int OFF_EDGES = OFF_NODES + NODES_SZ;
constexpr int OFF_RECV  = OFF_EDGES + EDGES_SZ;
constexpr int OFF_SEND  = OFF_RECV + BE_;
constexpr int OFF_GLOB  = OFF_SEND + BE_;
constexpr int OFF_NGI   = OFF_GLOB + GLOB_SZ;
constexpr int OFF_EGI   = OFF_NGI + BN_;

// prep_all region boundaries (thread indices)
constexpr int NT_CH   = NODES_SZ / 8;                // 524288 nodes chunks
constexpr int GL_CH   = GLOB_SZ / 8;                 // 8192 glob chunks
constexpr int RW_END  = 114688;                      // weights (1/thread)
constexpr int RB_END  = RW_END + (NT_CH + GL_CH) / 4;   // 247808
constexpr int RC_END  = RB_END + (EDGES_SZ / 8) / 4;    // 772096
constexpr int RD_END  = RC_END + (3 * BE_ + BN_) / 4;   // 878592
constexpr int RE_END  = RD_END + BE_;                   // 1009664

// ws layout (float-element offsets)
constexpr int WS_EAGGP = 0;                          // [PART][BG][DD] f32
constexpr int WS_NAGGP = WS_EAGGP + PART * GLOB_SZ;
constexpr int WS_CNT   = WS_NAGGP + PART * GLOB_SZ;  // int [B*N] (memset 0)
constexpr int WS_GCNTE = WS_CNT + BN_;               // int [512] (memset 0)
constexpr int WS_GCNTN = WS_GCNTE + 512;             // int [512] (memset 0)
constexpr int WS_CUR   = WS_GCNTN + 512;             // int [B*N]
constexpr int WS_GCURE = WS_CUR + BN_;               // int [512]
constexpr int WS_GCURN = WS_GCURE + 512;             // int [512]
constexpr int WS_ELIST = WS_GCURN + 512;             // int [B*E]
constexpr int WS_GELE  = WS_ELIST + BE_;             // int [B*E]
constexpr int WS_GELN  = WS_GELE + BE_;              // int [B*N]
constexpr int WS_ADJB  = WS_GELN + BN_;              // (unused)
constexpr int WS_NODB  = WS_ADJB + (BN_ * DD) / 2;   // u16 [B,N,D]
constexpr int WS_GLOBB = WS_NODB + (BN_ * DD) / 2;   // u16 [B,G,D]
constexpr int WS_WET   = WS_GLOBB + GLOB_SZ / 2;     // u16 [128*512] swz image
constexpr int WS_WNT   = WS_WET + 32768;             // u16 [128*384] swz image
constexpr int WS_UEB   = WS_WNT + 24576;             // u16 [B,E,D] bf16 u_e
constexpr int WS_EDGB  = WS_UEB + (BE_ * DD) / 2;    // u16 [B,E,D] edgesB; uNb aliases

__device__ inline u16 f2bf(float f) {
    union { float f; unsigned u; } v; v.f = f;
    return (u16)((v.u + 0x7fffu + ((v.u >> 16) & 1u)) >> 16);
}
__device__ inline float bf2f(u16 h) {
    union { unsigned u; float f; } v; v.u = ((unsigned)h) << 16; return v.f;
}
__device__ inline short8 pack8(float4 a, float4 b) {
    short8 r;
    r[0] = (short)f2bf(a.x); r[1] = (short)f2bf(a.y);
    r[2] = (short)f2bf(a.z); r[3] = (short)f2bf(a.w);
    r[4] = (short)f2bf(b.x); r[5] = (short)f2bf(b.y);
    r[6] = (short)f2bf(b.z); r[7] = (short)f2bf(b.w);
    return r;
}

// -------- fused prep + LDS-aggregated histogram tail (R20) --------
__global__ __launch_bounds__(256) void prep_all(
    const float* __restrict__ We, const float* __restrict__ Wn,
    u16* __restrict__ WeT2, u16* __restrict__ WnT2,
    const float* __restrict__ nodes, const float* __restrict__ glob,
    const float* __restrict__ edges,
    u16* __restrict__ nodesB, u16* __restrict__ globB, u16* __restrict__ edgesB,
    const int* __restrict__ recv, const int* __restrict__ send,
    const int* __restrict__ ngi, const int* __restrict__ egi,
    float* __restrict__ out,
    int* __restrict__ cnt, int* __restrict__ gcnt_e, int* __restrict__ gcnt_n) {
    __shared__ int lh[128];
    const int tid = threadIdx.x;
    const int i = blockIdx.x * 256 + tid;
    if (i < RW_END) {
        if (i < 65536) {
            const int ch = i >> 15;
            const int r = i & 32767;
            const int row = r >> 9;
            const int inb = (r << 1) & 1023;
            const int kb = inb ^ ((row & 7) << 4);
            WeT2[i] = f2bf(We[(kb >> 1) * DD + ch * 64 + row]);
        } else {
            const int q = i - 65536;
            const int ch = q / 24576;
            const int r = q % 24576;
            const int row = r / 384;
            const int inb = (r % 384) << 1;
            const int kb = inb ^ ((row & 7) << 4);
            WnT2[q] = f2bf(Wn[(kb >> 1) * DD + ch * 64 + row]);
        }
    } else if (i < RB_END) {
        const long c0 = ((long)(i - RW_END)) << 2;
        if (c0 < NT_CH) {
            float4 a[4], b[4];
            #pragma unroll
            for (int t = 0; t < 4; ++t) {
                a[t] = *(const float4*)(nodes + (c0 + t) * 8);
                b[t] = *(const float4*)(nodes + (c0 + t) * 8 + 4);
            }
            #pragma unroll
            for (int t = 0; t < 4; ++t)
                *(short8*)(nodesB + (c0 + t) * 8) = pack8(a[t], b[t]);
        } else {
            const long c2 = c0 - NT_CH;
            float4 a[4], b[4];
            #pragma unroll
            for (int t = 0; t < 4; ++t) {
                a[t] = *(const float4*)(glob + (c2 + t) * 8);
                b[t] = *(const float4*)(glob + (c2 + t) * 8 + 4);
            }
            #pragma unroll
            for (int t = 0; t < 4; ++t)
                *(short8*)(globB + (c2 + t) * 8) = pack8(a[t], b[t]);
        }
    } else if (i < RC_END) {
        const long c0 = ((long)(i - RB_END)) << 2;
        float4 a[4], b[4];
        #pragma unroll
        for (int t = 0; t < 4; ++t) {
            a[t] = *(const float4*)(edges + (c0 + t) * 8);
            b[t] = *(const float4*)(edges + (c0 + t) * 8 + 4);
        }
        #pragma unroll
        for (int t = 0; t < 4; ++t)
            *(short8*)(edgesB + (c0 + t) * 8) = pack8(a[t], b[t]);
    } else if (i < RD_END) {
        const int k = (i - RC_END) << 2;
        const int* src;
        long dst;
        int loc;
        if (k < BE_)                 { src = recv; loc = k;               dst = OFF_RECV + loc; }
        else if (k < 2 * BE_)        { src = send; loc = k - BE_;         dst = OFF_SEND + loc; }
        else if (k < 2 * BE_ + BN_)  { src = ngi;  loc = k - 2 * BE_;     dst = OFF_NGI + loc; }
        else                         { src = egi;  loc = k - 2 * BE_ - BN_; dst = OFF_EGI + loc; }
        const int4 v = *(const int4*)(src + loc);
        float4 o;
        o.x = (float)v.x; o.y = (float)v.y; o.z = (float)v.z; o.w = (float)v.w;
        *(float4*)(out + dst) = o;
    } else {
        const int k3 = i - RD_END;                  // < BE_
        const int b = k3 >> 14;
        const int k30 = blockIdx.x * 256 - RD_END;  // block's first k3
        const bool isnb = (k30 < BN_);
        if (tid < 128) lh[tid] = 0;
        __syncthreads();
        atomicAdd(&cnt[b * N_ + recv[k3]], 1);
        atomicAdd(&lh[egi[k3]], 1);
        if (isnb) atomicAdd(&lh[64 + ngi[k3]], 1);
        __syncthreads();
        if (tid < 64) {
            const int v = lh[tid];
            if (v) atomicAdd(&gcnt_e[b * G_ + tid], v);
        } else if (tid < 128 && isnb) {
            const int v = lh[tid];
            if (v) atomicAdd(&gcnt_n[(k30 >> 12) * G_ + (tid - 64)], v);
        }
    }
}

__global__ __launch_bounds__(1024) void k_scan(
    const int* __restrict__ cnt, int* __restrict__ cur,
    const int* __restrict__ gcnt_e, int* __restrict__ gcur_e,
    const int* __restrict__ gcnt_n, int* __restrict__ gcur_n) {
    __shared__ int s[1024];
    const int b = blockIdx.x;
    const int t = threadIdx.x;
    const int base = b * N_;
    int c[4];
    int sum = 0;
    #pragma unroll
    for (int i = 0; i < 4; ++i) { c[i] = cnt[base + 4 * t + i]; sum += c[i]; }
    s[t] = sum;
    __syncthreads();
    for (int off = 1; off < 1024; off <<= 1) {
        int v = s[t];
        if (t >= off) v += s[t - off];
        __syncthreads();
        s[t] = v;
        __syncthreads();
    }
    int eb = s[t] - sum;
    #pragma unroll
    for (int i = 0; i < 4; ++i) { cur[base + 4 * t + i] = eb; eb += c[i]; }
    __syncthreads();
    int gv = 0;
    if (t < G_) { gv = gcnt_e[b * G_ + t]; s[t] = gv; }
    __syncthreads();
    for (int off = 1; off < G_; off <<= 1) {
        int v = 0;
        if (t < G_) { v = s[t]; if (t >= off) v += s[t - off]; }
        __syncthreads();
        if (t < G_) s[t] = v;
        __syncthreads();
    }
    if (t < G_) gcur_e[b * G_ + t] = s[t] - gv;
    __syncthreads();
    if (t < G_) { gv = gcnt_n[b * G_ + t]; s[t] = gv; }
    __syncthreads();
    for (int off = 1; off < G_; off <<= 1) {
        int v = 0;
        if (t < G_) { v = s[t]; if (t >= off) v += s[t - off]; }
        __syncthreads();
        if (t < G_) s[t] = v;
        __syncthreads();
    }
    if (t < G_) gcur_n[b * G_ + t] = s[t] - gv;
}

// -------- fill: LDS range-reservation for gelist (R20) --------
__global__ __launch_bounds__(256) void k_fill_all(
    const int* __restrict__ recv, const int* __restrict__ egi,
    const int* __restrict__ ngi,
    int* __restrict__ cur, int* __restrict__ elist,
    int* __restrict__ gcur_e, int* __restrict__ gelist_e,
    int* __restrict__ gcur_n, int* __restrict__ gelist_n) {
    __shared__ int lcnt[128], lbase[128];
    const int tid = threadIdx.x;
    const int i = blockIdx.x * 256 + tid;
    const int b = i >> 14;
    const int i0 = blockIdx.x * 256;
    const bool isnb = (i0 < BN_);
    if (tid < 128) lcnt[tid] = 0;
    __syncthreads();
    const int s1 = atomicAdd(&cur[b * N_ + recv[i]], 1);
    elist[b * E_ + s1] = i;
    const int ge = egi[i];
    const int loc_e = atomicAdd(&lcnt[ge], 1);
    int gn = 0, loc_n = 0;
    if (isnb) { gn = ngi[i]; loc_n = atomicAdd(&lcnt[64 + gn], 1); }
    __syncthreads();
    if (tid < 64) {
        const int v = lcnt[tid];
        if (v) lbase[tid] = atomicAdd(&gcur_e[b * G_ + tid], v);
    } else if (tid < 128 && isnb) {
        const int v = lcnt[tid];
        if (v) lbase[tid] = atomicAdd(&gcur_n[(i0 >> 12) * G_ + (tid - 64)], v);
    }
    __syncthreads();
    gelist_e[(long)b * E_ + lbase[ge] + loc_e] = i;
    if (isnb) gelist_n[(long)(i0 >> 12) * N_ + lbase[64 + gn] + loc_n] = i;
}

// -------- edge GEMM: R15 structure + counted-vmcnt pipeline (T3/T4) -------
__global__ __launch_bounds__(256, 3) void edge_mfma(
    const u16* __restrict__ edgesB, const u16* __restrict__ nodesB,
    const u16* __restrict__ globB,
    const int* __restrict__ receivers, const int* __restrict__ senders,
    const int* __restrict__ egi,
    const u16* __restrict__ WeT2, const float* __restrict__ be,
    const float* __restrict__ w_res,
    float* __restrict__ outE, u16* __restrict__ uEb) {
    __shared__ u16 As[2][128 * 64];            // 2 x 16 KB (rows x 128B)
    __shared__ u16 Bs[2][64 * 64];             // 2 x 8 KB  (cols x 128B)
    const int tid = threadIdx.x;
    const int bid = blockIdx.x;                // 2048
    const int bb = bid & 7;                    // batch = XCD
    const int q = bid >> 3;                    // 0..255
    const int ch = q & 1;
    const int rt = q >> 1;                     // 0..127
    const int row0 = bb * E_ + rt * 128;

    const int wv = tid >> 6, l = tid & 63;
    const int fr = l & 15, fg = l >> 4;
    const int lrow0 = wv * 32 + fr;            // 0..127
    const int R0 = row0 + lrow0, R1 = R0 + 16;

    const char* img = (const char*)(WeT2 + (long)ch * 32768);
    const int swz = (fr & 7) << 4;

    auto stage = [&](int kk, int buf) {
        const int seg = kk >> 1, half = kk & 1;
        #pragma unroll
        for (int i = 0; i < 4; ++i) {          // A: 1024 chunks of 16B
            const int gci = i * 256 + tid;
            const int r = gci >> 3, j = gci & 7;
            const int gr = row0 + r;
            const u16* rp;
            if (seg == 0)      rp = edgesB + (long)gr * DD;
            else if (seg == 1) rp = nodesB + ((long)bb * N_ + senders[gr]) * DD;
            else if (seg == 2) rp = nodesB + ((long)bb * N_ + receivers[gr]) * DD;
            else               rp = globB + ((long)bb * G_ + egi[gr]) * DD;
            const char* src = (const char*)rp + half * 128 +
                              ((j * 16) ^ ((r & 7) << 4));
            char* dst = (char*)As[buf] + r * 128 + j * 16;
            __builtin_amdgcn_global_load_lds(
                (const __attribute__((address_space(1))) void*)src,
                (__attribute__((address_space(3))) void*)dst, 16, 0, 0);
        }
        #pragma unroll
        for (int i = 0; i < 2; ++i) {          // B: 512 chunks of 16B
            const int gci = i * 256 + tid;
            const int col = gci >> 3, j = gci & 7;
            const char* src = img + (long)col * 1024 + kk * 128 + j * 16;
            char* dst = (char*)Bs[buf] + col * 128 + j * 16;
            __builtin_amdgcn_global_load_lds(
                (const __attribute__((address_space(1))) void*)src,
                (__attribute__((address_space(3))) void*)dst, 16, 0, 0);
        }
    };

    f32x4 acc0[4], acc1[4];
    const f32x4 fz = {0.f, 0.f, 0.f, 0.f};
    #pragma unroll
    for (int i = 0; i < 4; ++i) { acc0[i] = fz; acc1[i] = fz; }
    s16x4 eres0[4], eres1[4];

    stage(0, 0);
    asm volatile("s_waitcnt vmcnt(0)" ::: "memory");
    __builtin_amdgcn_s_barrier();
    __builtin_amdgcn_sched_barrier(0);

    #pragma unroll
    for (int kk = 0; kk < 8; ++kk) {
        const int buf = kk & 1;
        if (kk < 7) {
            stage(kk + 1, buf ^ 1);            // 6 loads fly across barriers
            __builtin_amdgcn_sched_barrier(0);
            asm volatile("s_waitcnt vmcnt(6)" ::: "memory");  // stage(kk) done
        } else {
            asm volatile("s_waitcnt vmcnt(0)" ::: "memory");
        }
        __builtin_amdgcn_s_barrier();          // tile kk ready (all waves)
        __builtin_amdgcn_sched_barrier(0);     // pin ds_reads below (rule 18)
        __builtin_amdgcn_s_setprio(1);
        #pragma unroll
        for (int ss = 0; ss < 2; ++ss) {
            const int ko = (ss * 64 + fg * 16) ^ swz;
            const short8 a0 = *(const short8*)((char*)As[buf] + lrow0 * 128 + ko);
            const short8 a1 = *(const short8*)((char*)As[buf] + (lrow0 + 16) * 128 + ko);
            #pragma unroll
            for (int nt = 0; nt < 4; ++nt) {
                const short8 b = *(const short8*)((char*)Bs[buf] + (nt * 16 + fr) * 128 + ko);
                acc0[nt] = __builtin_amdgcn_mfma_f32_16x16x32_bf16(b, a0, acc0[nt], 0, 0, 0);
                acc1[nt] = __builtin_amdgcn_mfma_f32_16x16x32_bf16(b, a1, acc1[nt], 0, 0, 0);
            }
        }
        __builtin_amdgcn_s_setprio(0);
        if (kk == ch) {
            #pragma unroll
            for (int nt = 0; nt < 4; ++nt) {
                const int jb = (nt * 32 + fg * 8) ^ swz;
                eres0[nt] = *(const s16x4*)((char*)As[buf] + lrow0 * 128 + jb);
                eres1[nt] = *(const s16x4*)((char*)As[buf] + (lrow0 + 16) * 128 + jb);
            }
        }
        if (kk < 7) {
            __builtin_amdgcn_sched_barrier(0);
            __builtin_amdgcn_s_barrier();      // all waves done reading buf
        }
    }

    const float wr = w_res[0];
    #pragma unroll
    for (int nt = 0; nt < 4; ++nt) {
        const int c = ch * 64 + nt * 16 + fg * 4;
        const float4 bv = *(const float4*)(be + c);
        const float u00 = fmaxf(acc0[nt][0] + bv.x, 0.f);
        const float u01 = fmaxf(acc0[nt][1] + bv.y, 0.f);
        const float u02 = fmaxf(acc0[nt][2] + bv.z, 0.f);
        const float u03 = fmaxf(acc0[nt][3] + bv.w, 0.f);
        const float u10 = fmaxf(acc1[nt][0] + bv.x, 0.f);
        const float u11 = fmaxf(acc1[nt][1] + bv.y, 0.f);
        const float u12 = fmaxf(acc1[nt][2] + bv.z, 0.f);
        const float u13 = fmaxf(acc1[nt][3] + bv.w, 0.f);
        s16x4 h0, h1;
        h0[0] = (short)f2bf(u00); h0[1] = (short)f2bf(u01);
        h0[2] = (short)f2bf(u02); h0[3] = (short)f2bf(u03);
        h1[0] = (short)f2bf(u10); h1[1] = (short)f2bf(u11);
        h1[2] = (short)f2bf(u12); h1[3] = (short)f2bf(u13);
        *(s16x4*)(uEb + (long)R0 * DD + c) = h0;
        *(s16x4*)(uEb + (long)R1 * DD + c) = h1;
        float4 o0, o1;
        o0.x = bf2f((u16)eres0[nt][0]) + wr * u00;
        o0.y = bf2f((u16)eres0[nt][1]) + wr * u01;
        o0.z = bf2f((u16)eres0[nt][2]) + wr * u02;
        o0.w = bf2f((u16)eres0[nt][3]) + wr * u03;
        o1.x = bf2f((u16)eres1[nt][0]) + wr * u10;
        o1.y = bf2f((u16)eres1[nt][1]) + wr * u11;
        o1.z = bf2f((u16)eres1[nt][2]) + wr * u12;
        o1.w = bf2f((u16)eres1[nt][3]) + wr * u13;
        *(float4*)(outE + (long)R0 * DD + c) = o0;
        *(float4*)(outE + (long)R1 * DD + c) = o1;
    }
}

// -------- merged: node GEMM (blocks 0..511) + eagg gather (512..2559) -----
__global__ __launch_bounds__(256, 3) void node_agge(
    const u16* __restrict__ nodesB, const u16* __restrict__ uEb,
    const u16* __restrict__ globB, const int* __restrict__ ngi,
    const int* __restrict__ cnt, const int* __restrict__ cur,
    const int* __restrict__ elist,
    const u16* __restrict__ WnT2, const float* __restrict__ bn,
    const float* __restrict__ nodes, const float* __restrict__ w_res,
    float* __restrict__ outN, u16* __restrict__ uNb,
    const int* __restrict__ gcnt_e, const int* __restrict__ gcur_e,
    const int* __restrict__ gelist_e, float* __restrict__ eaggp) {
    __shared__ char smem[64 * 384 * 2];        // 48 KB (union)
    const int tid = threadIdx.x;

    if (blockIdx.x >= 512) {
        float* accl = (float*)smem;
        const int abid = blockIdx.x - 512;     // 0..2047
        const int bg = abid >> 2;
        const int p  = abid & 3;
        const int b = bg >> 6;
        const int c4 = (tid & 31) << 2;
        const int sub = tid >> 5;
        const int m = gcnt_e[bg];
        const int* lp = gelist_e + (long)b * E_ + (gcur_e[bg] - m);
        f32x4 acc = {0.f, 0.f, 0.f, 0.f};
        for (int j = p * 8 + sub; j < m; j += 32) {
            const u16* up = uEb + (long)lp[j] * DD + c4;
            const s16x4 v = *(const s16x4*)up;
            acc[0] += bf2f((u16)v[0]); acc[1] += bf2f((u16)v[1]);
            acc[2] += bf2f((u16)v[2]); acc[3] += bf2f((u16)v[3]);
        }
        *(f32x4*)&accl[sub * 128 + c4] = acc;
        __syncthreads();
        if (tid < 128) {
            float s = 0.f;
            #pragma unroll
            for (int q2 = 0; q2 < 8; ++q2) s += accl[q2 * 128 + tid];
            eaggp[((long)p * BG_ + bg) * DD + tid] = s;
        }
        return;
    }

    u16* Bs = (u16*)smem;                      // [64*384]
    const int bid = blockIdx.x;                // 0..511
    const int bb = bid & 7;
    const int jj = bid >> 3;
    const int ch = jj & 1;
    const int rt = jj >> 1;
    const int row0 = bb * N_ + rt * 128;

    const int wv = tid >> 6, l = tid & 63;
    const int fr = l & 15, fg = l >> 4;
    const int rowbase = row0 + wv * 32;
    const int R0 = rowbase + fr, R1 = R0 + 16;

    {
        const char* wsrc = (const char*)(WnT2 + (long)ch * 24576) + l * 16;
        char* ldst = (char*)Bs;
        #pragma unroll
        for (int i2 = 0; i2 < 12; ++i2) {
            const int off = (wv * 12 + i2) * 1024;
            __builtin_amdgcn_global_load_lds(
                (const __attribute__((address_space(1))) void*)(wsrc + off),
                (__attribute__((address_space(3))) void*)(ldst + off),
                16, 0, 0);
        }
    }

    const u16* pN0 = nodesB + (long)R0 * DD;
    const u16* pN1 = nodesB + (long)R1 * DD;
    const u16* pG0 = globB + ((long)bb * G_ + ngi[R0]) * DD;
    const u16* pG1 = globB + ((long)bb * G_ + ngi[R1]) * DD;
    short8 PN0[4], PN1[4], PG0[4], PG1[4], PA0[4], PA1[4];
    #pragma unroll
    for (int ss = 0; ss < 4; ++ss) {
        PN0[ss] = *(const short8*)(pN0 + ss * 32 + fg * 8);
        PN1[ss] = *(const short8*)(pN1 + ss * 32 + fg * 8);
        PG0[ss] = *(const short8*)(pG0 + ss * 32 + fg * 8);
        PG1[ss] = *(const short8*)(pG1 + ss * 32 + fg * 8);
    }

    {
        float ga[32];
        const int deg0 = cnt[R0];
        const int* lp0 = elist + (long)bb * E_ + (cur[R0] - deg0);
        #pragma unroll
        for (int j = 0; j < 32; ++j) ga[j] = 0.f;
        for (int i = 0; i < deg0; ++i) {
            const u16* up = uEb + (long)lp0[i] * DD + fg * 8;
            #pragma unroll
            for (int ss = 0; ss < 4; ++ss) {
                const short8 v = *(const short8*)(up + ss * 32);
                #pragma unroll
                for (int e2 = 0; e2 < 8; ++e2) ga[ss * 8 + e2] += bf2f((u16)v[e2]);
            }
        }
        #pragma unroll
        for (int ss = 0; ss < 4; ++ss) {
            short8 h;
            #pragma unroll
            for (int e2 = 0; e2 < 8; ++e2) h[e2] = (short)f2bf(ga[ss * 8 + e2]);
            PA0[ss] = h;
        }
        const int deg1 = cnt[R1];
        const int* lp1 = elist + (long)bb * E_ + (cur[R1] - deg1);
        #pragma unroll
        for (int j = 0; j < 32; ++j) ga[j] = 0.f;
        for (int i = 0; i < deg1; ++i) {
            const u16* up = uEb + (long)lp1[i] * DD + fg * 8;
            #pragma unroll
            for (int ss = 0; ss < 4; ++ss) {
                const short8 v = *(const short8*)(up + ss * 32);
                #pragma unroll
                for (int e2 = 0; e2 < 8; ++e2) ga[ss * 8 + e2] += bf2f((u16)v[e2]);
            }
        }
        #pragma unroll
        for (int ss = 0; ss < 4; ++ss) {
            short8 h;
            #pragma unroll
            for (int e2 = 0; e2 < 8; ++e2) h[e2] = (short)f2bf(ga[ss * 8 + e2]);
            PA1[ss] = h;
        }
    }

    f32x4 acc0[4], acc1[4];
    const f32x4 fz = {0.f, 0.f, 0.f, 0.f};
    #pragma unroll
    for (int i = 0; i < 4; ++i) { acc0[i] = fz; acc1[i] = fz; }

    __syncthreads();

    const char* bsp = (const char*)Bs;
    const int swr = (fr & 7) << 4;
    #pragma unroll
    for (int seg = 0; seg < 3; ++seg) {
        __builtin_amdgcn_s_setprio(1);
        #pragma unroll
        for (int ss = 0; ss < 4; ++ss) {
            const short8 a0 = (seg == 0) ? PN0[ss] : (seg == 1) ? PA0[ss] : PG0[ss];
            const short8 a1 = (seg == 0) ? PN1[ss] : (seg == 1) ? PA1[ss] : PG1[ss];
            #pragma unroll
            for (int nt = 0; nt < 4; ++nt) {
                const int addr = (nt * 16 + fr) * 768 +
                                 ((seg * 256 + ss * 64 + fg * 16) ^ swr);
                const short8 b = *(const short8*)(bsp + addr);
                acc0[nt] = __builtin_amdgcn_mfma_f32_16x16x32_bf16(b, a0, acc0[nt], 0, 0, 0);
                acc1[nt] = __builtin_amdgcn_mfma_f32_16x16x32_bf16(b, a1, acc1[nt], 0, 0, 0);
            }
        }
        __builtin_amdgcn_s_setprio(0);
    }

    const float wr = w_res[0];
    #pragma unroll
    for (int nt = 0; nt < 4; ++nt) {
        const int c = ch * 64 + nt * 16 + fg * 4;
        const float4 bv = *(const float4*)(bn + c);
        const float4 n0 = *(const float4*)(nodes + (long)R0 * DD + c);
        const float4 n1 = *(const float4*)(nodes + (long)R1 * DD + c);
        const float u00 = fmaxf(acc0[nt][0] + bv.x, 0.f);
        const float u01 = fmaxf(acc0[nt][1] + bv.y, 0.f);
        const float u02 = fmaxf(acc0[nt][2] + bv.z, 0.f);
        const float u03 = fmaxf(acc0[nt][3] + bv.w, 0.f);
        const float u10 = fmaxf(acc1[nt][0] + bv.x, 0.f);
        const float u11 = fmaxf(acc1[nt][1] + bv.y, 0.f);
        const float u12 = fmaxf(acc1[nt][2] + bv.z, 0.f);
        const float u13 = fmaxf(acc1[nt][3] + bv.w, 0.f);
        s16x4 h0, h1;
        h0[0] = (short)f2bf(u00); h0[1] = (short)f2bf(u01);
        h0[2] = (short)f2bf(u02); h0[3] = (short)f2bf(u03);
        h1[0] = (short)f2bf(u10); h1[1] = (short)f2bf(u11);
        h1[2] = (short)f2bf(u12); h1[3] = (short)f2bf(u13);
        *(s16x4*)(uNb + (long)R0 * DD + c) = h0;
        *(s16x4*)(uNb + (long)R1 * DD + c) = h1;
        float4 o0, o1;
        o0.x = n0.x + wr * u00; o0.y = n0.y + wr * u01;
        o0.z = n0.z + wr * u02; o0.w = n0.w + wr * u03;
        o1.x = n1.x + wr * u10; o1.y = n1.y + wr * u11;
        o1.z = n1.z + wr * u12; o1.w = n1.w + wr * u13;
        *(float4*)(outN + (long)R0 * DD + c) = o0;
        *(float4*)(outN + (long)R1 * DD + c) = o1;
    }
}

// -------- agg = per-(b,g) gather-sum of bf16 u rows (node aggregate) ------
__global__ __launch_bounds__(256) void agg_only(
    const int* __restrict__ gcnt, const int* __restrict__ gcur,
    const int* __restrict__ gelist, int spb, const u16* __restrict__ uB,
    float* __restrict__ aggp /* [PART][BG][DD] */) {
    __shared__ float accl[1024];
    const int bg = blockIdx.x >> 2;            // grid = BG*PART
    const int p  = blockIdx.x & 3;
    const int b = bg >> 6;
    const int tid = threadIdx.x;
    const int c4 = (tid & 31) << 2;
    const int sub = tid >> 5;                  // 0..7
    const int m = gcnt[bg];
    const int* lp = gelist + (long)b * spb + (gcur[bg] - m);
    f32x4 acc = {0.f, 0.f, 0.f, 0.f};
    for (int j = p * 8 + sub; j < m; j += 32) {
        const u16* up = uB + (long)lp[j] * DD + c4;
        const s16x4 v = *(const s16x4*)up;
        acc[0] += bf2f((u16)v[0]); acc[1] += bf2f((u16)v[1]);
        acc[2] += bf2f((u16)v[2]); acc[3] += bf2f((u16)v[3]);
    }
    *(f32x4*)&accl[sub * 128 + c4] = acc;
    __syncthreads();
    if (tid < 128) {
        float s = 0.f;
        #pragma unroll
        for (int q2 = 0; q2 < 8; ++q2) s += accl[q2 * 128 + tid];
        aggp[((long)p * BG_ + bg) * DD + tid] = s;
    }
}

// ---------------- global block: 512 rows, K=384, fp32 VALU ----------------
__global__ __launch_bounds__(128) void global_block(
    const float* __restrict__ naggp, const float* __restrict__ eaggp,
    const float* __restrict__ glob,
    const float* __restrict__ Wg, const float* __restrict__ bgb,
    const float* __restrict__ w_res, float* __restrict__ out) {
    __shared__ float gin[384];
    const int row = blockIdx.x;
    const int tid = threadIdx.x;
    float sn = 0.f, se = 0.f;
    #pragma unroll
    for (int p = 0; p < PART; ++p) {
        sn += naggp[((long)p * BG_ + row) * DD + tid];
        se += eaggp[((long)p * BG_ + row) * DD + tid];
    }
    gin[tid]       = sn;
    gin[128 + tid] = se;
    gin[256 + tid] = glob[row * DD + tid];
    __syncthreads();
    float acc = bgb[tid];
    #pragma unroll 4
    for (int k = 0; k < 384; ++k) acc += gin[k] * Wg[k * DD + tid];
    const float upd = fmaxf(acc, 0.f);
    out[OFF_GLOB + row * DD + tid] = glob[row * DD + tid] + w_res[0] * upd;
}

extern "C" void kernel_launch(void* const* d_in, const int* in_sizes, int n_in,
                              void* d_out, int out_size, void* d_ws, size_t ws_size,
                              hipStream_t stream) {
    const float* nodes     = (const float*)d_in[0];
    const float* edges     = (const float*)d_in[1];
    const int*   receivers = (const int*)d_in[2];
    const int*   senders   = (const int*)d_in[3];
    const float* glob      = (const float*)d_in[4];
    const int*   ngi       = (const int*)d_in[5];
    const int*   egi       = (const int*)d_in[6];
    const float* We        = (const float*)d_in[7];
    const float* be        = (const float*)d_in[8];
    const float* Wn        = (const float*)d_in[9];
    const float* bn        = (const float*)d_in[10];
    const float* Wg        = (const float*)d_in[11];
    const float* bg        = (const float*)d_in[12];
    const float* w_res     = (const float*)d_in[13];
    float* out = (float*)d_out;
    float* ws  = (float*)d_ws;

    float* eaggp = ws + WS_EAGGP;
    float* naggp = ws + WS_NAGGP;
    int* cnt      = (int*)(ws + WS_CNT);
    int* gcnt_e   = (int*)(ws + WS_GCNTE);
    int* gcnt_n   = (int*)(ws + WS_GCNTN);
    int* cur      = (int*)(ws + WS_CUR);
    int* gcur_e   = (int*)(ws + WS_GCURE);
    int* gcur_n   = (int*)(ws + WS_GCURN);
    int* elist    = (int*)(ws + WS_ELIST);
    int* gelist_e = (int*)(ws + WS_GELE);
    int* gelist_n = (int*)(ws + WS_GELN);
    u16* nodesB = (u16*)(ws + WS_NODB);
    u16* globB  = (u16*)(ws + WS_GLOBB);
    u16* WeT2   = (u16*)(ws + WS_WET);
    u16* WnT2   = (u16*)(ws + WS_WNT);
    u16* uEb    = (u16*)(ws + WS_UEB);
    u16* edgesB = (u16*)(ws + WS_EDGB);
    u16* uNb    = (u16*)(ws + WS_EDGB);  // reuses edgesB region (consumed)

    float* outE = out + OFF_EDGES;
    float* outN = out + OFF_NODES;

    hipMemsetAsync(cnt, 0, (size_t)(BN_ + 1024) * sizeof(int), stream);

    hipLaunchKernelGGL(prep_all, dim3(RE_END / 256), dim3(256), 0, stream,
                       We, Wn, WeT2, WnT2, nodes, glob, edges,
                       nodesB, globB, edgesB,
                       receivers, senders, ngi, egi, out,
                       cnt, gcnt_e, gcnt_n);
    hipLaunchKernelGGL(k_scan, dim3(8), dim3(1024), 0, stream,
                       cnt, cur, gcnt_e, gcur_e, gcnt_n, gcur_n);
    hipLaunchKernelGGL(k_fill_all, dim3(512), dim3(256), 0, stream,
                       receivers, egi, ngi, cur, elist, gcur_e, gelist_e,
                       gcur_n, gelist_n);
    hipLaunchKernelGGL(edge_mfma, dim3(2048), dim3(256), 0, stream,
                       edgesB, nodesB, globB, receivers, senders, egi,
                       WeT2, be, w_res, outE, uEb);
    hipLaunchKernelGGL(node_agge, dim3(2560), dim3(256), 0, stream,
                       nodesB, uEb, globB, ngi, cnt, cur, elist,
                       WnT2, bn, nodes, w_res, outN, uNb,
                       gcnt_e, gcur_e, gelist_e, eaggp);
    hipLaunchKernelGGL(agg_only, dim3(BG_ * PART), dim3(256), 0, stream,
                       gcnt_n, gcur_n, gelist_n, N_, uNb, naggp);
    hipLaunchKernelGGL(global_block, dim3(BG_), dim3(128), 0, stream,
                       naggp, eaggp, glob, Wg, bg, w_res, out);
}

// Round 22
// 165.198 us; speedup vs baseline: 1.3903x; 1.0138x over previous
//
#include <hip/hip_runtime.h>

// GraphNetworkLayer: B=8, N=4096, E=16384, G=64, D=128, fp32 in/out.
// Round 22: R21 config with ONE delta — edge_mfma epilogue bounces outputs
// through the (dead after K-loop) As/Bs LDS, then copies out linearly:
// outE rows as 256B-contiguous float4 runs, uEb rows as 128B short8 runs
// (was per-lane 16B/8B stores scattered across 16 rows per instruction).
// All other kernels byte-identical to R21.

#define DD 128
typedef unsigned short u16;
typedef __attribute__((ext_vector_type(8))) short short8;   // 8 bf16
typedef __attribute__((ext_vector_type(4))) short s16x4;    // 4 bf16
typedef __attribute__((ext_vector_type(4))) float f32x4;

constexpr int B_ = 8, N_ = 4096, E_ = 16384, G_ = 64;
constexpr int NODES_SZ = B_ * N_ * DD;   // 4,194,304
constexpr int EDGES_SZ = B_ * E_ * DD;   // 16,777,216
constexpr int BE_ = B_ * E_;             // 131,072
constexpr int BN_ = B_ * N_;             // 32,768
constexpr int BG_ = B_ * G_;             // 512
constexpr int GLOB_SZ = BG_ * DD;        // 65,536
constexpr int PART = 4;

constexpr int OFF_NODES = 0;
constexpr int OFF_EDGES = OFF_NODES + NODES_SZ;
constexpr int OFF_RECV  = OFF_EDGES + EDGES_SZ;
constexpr int OFF_SEND  = OFF_RECV + BE_;
constexpr int OFF_GLOB  = OFF_SEND + BE_;
constexpr int OFF_NGI   = OFF_GLOB + GLOB_SZ;
constexpr int OFF_EGI   = OFF_NGI + BN_;

// prep_all region boundaries (thread indices)
constexpr int NT_CH   = NODES_SZ / 8;                // 524288 nodes chunks
constexpr int GL_CH   = GLOB_SZ / 8;                 // 8192 glob chunks
constexpr int RW_END  = 114688;                      // weights (1/thread)
constexpr int RB_END  = RW_END + (NT_CH + GL_CH) / 4;   // 247808
constexpr int RC_END  = RB_END + (EDGES_SZ / 8) / 4;    // 772096
constexpr int RD_END  = RC_END + (3 * BE_ + BN_) / 4;   // 878592
constexpr int RE_END  = RD_END + BE_;                   // 1009664

// ws layout (float-element offsets)
constexpr int WS_EAGGP = 0;                          // [PART][BG][DD] f32
constexpr int WS_NAGGP = WS_EAGGP + PART * GLOB_SZ;
constexpr int WS_CNT   = WS_NAGGP + PART * GLOB_SZ;  // int [B*N] (memset 0)
constexpr int WS_GCNTE = WS_CNT + BN_;               // int [512] (memset 0)
constexpr int WS_GCNTN = WS_GCNTE + 512;             // int [512] (memset 0)
constexpr int WS_CUR   = WS_GCNTN + 512;             // int [B*N]
constexpr int WS_GCURE = WS_CUR + BN_;               // int [512]
constexpr int WS_GCURN = WS_GCURE + 512;             // int [512]
constexpr int WS_ELIST = WS_GCURN + 512;             // int [B*E]
constexpr int WS_GELE  = WS_ELIST + BE_;             // int [B*E]
constexpr int WS_GELN  = WS_GELE + BE_;              // int [B*N]
constexpr int WS_ADJB  = WS_GELN + BN_;              // (unused)
constexpr int WS_NODB  = WS_ADJB + (BN_ * DD) / 2;   // u16 [B,N,D]
constexpr int WS_GLOBB = WS_NODB + (BN_ * DD) / 2;   // u16 [B,G,D]
constexpr int WS_WET   = WS_GLOBB + GLOB_SZ / 2;     // u16 [128*512] swz image
constexpr int WS_WNT   = WS_WET + 32768;             // u16 [128*384] swz image
constexpr int WS_UEB   = WS_WNT + 24576;             // u16 [B,E,D] bf16 u_e
constexpr int WS_EDGB  = WS_UEB + (BE_ * DD) / 2;    // u16 [B,E,D] edgesB; uNb aliases

__device__ inline u16 f2bf(float f) {
    union { float f; unsigned u; } v; v.f = f;
    return (u16)((v.u + 0x7fffu + ((v.u >> 16) & 1u)) >> 16);
}
__device__ inline float bf2f(u16 h) {
    union { unsigned u; float f; } v; v.u = ((unsigned)h) << 16; return v.f;
}
__device__ inline short8 pack8(float4 a, float4 b) {
    short8 r;
    r[0] = (short)f2bf(a.x); r[1] = (short)f2bf(a.y);
    r[2] = (short)f2bf(a.z); r[3] = (short)f2bf(a.w);
    r[4] = (short)f2bf(b.x); r[5] = (short)f2bf(b.y);
    r[6] = (short)f2bf(b.z); r[7] = (short)f2bf(b.w);
    return r;
}

// -------- fused prep + LDS-aggregated histogram tail (R20) --------
__global__ __launch_bounds__(256) void prep_all(
    const float* __restrict__ We, const float* __restrict__ Wn,
    u16* __restrict__ WeT2, u16* __restrict__ WnT2,
    const float* __restrict__ nodes, const float* __restrict__ glob,
    const float* __restrict__ edges,
    u16* __restrict__ nodesB, u16* __restrict__ globB, u16* __restrict__ edgesB,
    const int* __restrict__ recv, const int* __restrict__ send,
    const int* __restrict__ ngi, const int* __restrict__ egi,
    float* __restrict__ out,
    int* __restrict__ cnt, int* __restrict__ gcnt_e, int* __restrict__ gcnt_n) {
    __shared__ int lh[128];
    const int tid = threadIdx.x;
    const int i = blockIdx.x * 256 + tid;
    if (i < RW_END) {
        if (i < 65536) {
            const int ch = i >> 15;
            const int r = i & 32767;
            const int row = r >> 9;
            const int inb = (r << 1) & 1023;
            const int kb = inb ^ ((row & 7) << 4);
            WeT2[i] = f2bf(We[(kb >> 1) * DD + ch * 64 + row]);
        } else {
            const int q = i - 65536;
            const int ch = q / 24576;
            const int r = q % 24576;
            const int row = r / 384;
            const int inb = (r % 384) << 1;
            const int kb = inb ^ ((row & 7) << 4);
            WnT2[q] = f2bf(Wn[(kb >> 1) * DD + ch * 64 + row]);
        }
    } else if (i < RB_END) {
        const long c0 = ((long)(i - RW_END)) << 2;
        if (c0 < NT_CH) {
            float4 a[4], b[4];
            #pragma unroll
            for (int t = 0; t < 4; ++t) {
                a[t] = *(const float4*)(nodes + (c0 + t) * 8);
                b[t] = *(const float4*)(nodes + (c0 + t) * 8 + 4);
            }
            #pragma unroll
            for (int t = 0; t < 4; ++t)
                *(short8*)(nodesB + (c0 + t) * 8) = pack8(a[t], b[t]);
        } else {
            const long c2 = c0 - NT_CH;
            float4 a[4], b[4];
            #pragma unroll
            for (int t = 0; t < 4; ++t) {
                a[t] = *(const float4*)(glob + (c2 + t) * 8);
                b[t] = *(const float4*)(glob + (c2 + t) * 8 + 4);
            }
            #pragma unroll
            for (int t = 0; t < 4; ++t)
                *(short8*)(globB + (c2 + t) * 8) = pack8(a[t], b[t]);
        }
    } else if (i < RC_END) {
        const long c0 = ((long)(i - RB_END)) << 2;
        float4 a[4], b[4];
        #pragma unroll
        for (int t = 0; t < 4; ++t) {
            a[t] = *(const float4*)(edges + (c0 + t) * 8);
            b[t] = *(const float4*)(edges + (c0 + t) * 8 + 4);
        }
        #pragma unroll
        for (int t = 0; t < 4; ++t)
            *(short8*)(edgesB + (c0 + t) * 8) = pack8(a[t], b[t]);
    } else if (i < RD_END) {
        const int k = (i - RC_END) << 2;
        const int* src;
        long dst;
        int loc;
        if (k < BE_)                 { src = recv; loc = k;               dst = OFF_RECV + loc; }
        else if (k < 2 * BE_)        { src = send; loc = k - BE_;         dst = OFF_SEND + loc; }
        else if (k < 2 * BE_ + BN_)  { src = ngi;  loc = k - 2 * BE_;     dst = OFF_NGI + loc; }
        else                         { src = egi;  loc = k - 2 * BE_ - BN_; dst = OFF_EGI + loc; }
        const int4 v = *(const int4*)(src + loc);
        float4 o;
        o.x = (float)v.x; o.y = (float)v.y; o.z = (float)v.z; o.w = (float)v.w;
        *(float4*)(out + dst) = o;
    } else {
        const int k3 = i - RD_END;                  // < BE_
        const int b = k3 >> 14;
        const int k30 = blockIdx.x * 256 - RD_END;  // block's first k3
        const bool isnb = (k30 < BN_);
        if (tid < 128) lh[tid] = 0;
        __syncthreads();
        atomicAdd(&cnt[b * N_ + recv[k3]], 1);
        atomicAdd(&lh[egi[k3]], 1);
        if (isnb) atomicAdd(&lh[64 + ngi[k3]], 1);
        __syncthreads();
        if (tid < 64) {
            const int v = lh[tid];
            if (v) atomicAdd(&gcnt_e[b * G_ + tid], v);
        } else if (tid < 128 && isnb) {
            const int v = lh[tid];
            if (v) atomicAdd(&gcnt_n[(k30 >> 12) * G_ + (tid - 64)], v);
        }
    }
}

__global__ __launch_bounds__(1024) void k_scan(
    const int* __restrict__ cnt, int* __restrict__ cur,
    const int* __restrict__ gcnt_e, int* __restrict__ gcur_e,
    const int* __restrict__ gcnt_n, int* __restrict__ gcur_n) {
    __shared__ int s[1024];
    const int b = blockIdx.x;
    const int t = threadIdx.x;
    const int base = b * N_;
    int c[4];
    int sum = 0;
    #pragma unroll
    for (int i = 0; i < 4; ++i) { c[i] = cnt[base + 4 * t + i]; sum += c[i]; }
    s[t] = sum;
    __syncthreads();
    for (int off = 1; off < 1024; off <<= 1) {
        int v = s[t];
        if (t >= off) v += s[t - off];
        __syncthreads();
        s[t] = v;
        __syncthreads();
    }
    int eb = s[t] - sum;
    #pragma unroll
    for (int i = 0; i < 4; ++i) { cur[base + 4 * t + i] = eb; eb += c[i]; }
    __syncthreads();
    int gv = 0;
    if (t < G_) { gv = gcnt_e[b * G_ + t]; s[t] = gv; }
    __syncthreads();
    for (int off = 1; off < G_; off <<= 1) {
        int v = 0;
        if (t < G_) { v = s[t]; if (t >= off) v += s[t - off]; }
        __syncthreads();
        if (t < G_) s[t] = v;
        __syncthreads();
    }
    if (t < G_) gcur_e[b * G_ + t] = s[t] - gv;
    __syncthreads();
    if (t < G_) { gv = gcnt_n[b * G_ + t]; s[t] = gv; }
    __syncthreads();
    for (int off = 1; off < G_; off <<= 1) {
        int v = 0;
        if (t < G_) { v = s[t]; if (t >= off) v += s[t - off]; }
        __syncthreads();
        if (t < G_) s[t] = v;
        __syncthreads();
    }
    if (t < G_) gcur_n[b * G_ + t] = s[t] - gv;
}

// -------- fill: LDS range-reservation for gelist (R20) --------
__global__ __launch_bounds__(256) void k_fill_all(
    const int* __restrict__ recv, const int* __restrict__ egi,
    const int* __restrict__ ngi,
    int* __restrict__ cur, int* __restrict__ elist,
    int* __restrict__ gcur_e, int* __restrict__ gelist_e,
    int* __restrict__ gcur_n, int* __restrict__ gelist_n) {
    __shared__ int lcnt[128], lbase[128];
    const int tid = threadIdx.x;
    const int i = blockIdx.x * 256 + tid;
    const int b = i >> 14;
    const int i0 = blockIdx.x * 256;
    const bool isnb = (i0 < BN_);
    if (tid < 128) lcnt[tid] = 0;
    __syncthreads();
    const int s1 = atomicAdd(&cur[b * N_ + recv[i]], 1);
    elist[b * E_ + s1] = i;
    const int ge = egi[i];
    const int loc_e = atomicAdd(&lcnt[ge], 1);
    int gn = 0, loc_n = 0;
    if (isnb) { gn = ngi[i]; loc_n = atomicAdd(&lcnt[64 + gn], 1); }
    __syncthreads();
    if (tid < 64) {
        const int v = lcnt[tid];
        if (v) lbase[tid] = atomicAdd(&gcur_e[b * G_ + tid], v);
    } else if (tid < 128 && isnb) {
        const int v = lcnt[tid];
        if (v) lbase[tid] = atomicAdd(&gcur_n[(i0 >> 12) * G_ + (tid - 64)], v);
    }
    __syncthreads();
    gelist_e[(long)b * E_ + lbase[ge] + loc_e] = i;
    if (isnb) gelist_n[(long)(i0 >> 12) * N_ + lbase[64 + gn] + loc_n] = i;
}

// -------- edge GEMM: R21 pipeline + LDS-bounce coalesced epilogue ---------
__global__ __launch_bounds__(256, 3) void edge_mfma(
    const u16* __restrict__ edgesB, const u16* __restrict__ nodesB,
    const u16* __restrict__ globB,
    const int* __restrict__ receivers, const int* __restrict__ senders,
    const int* __restrict__ egi,
    const u16* __restrict__ WeT2, const float* __restrict__ be,
    const float* __restrict__ w_res,
    float* __restrict__ outE, u16* __restrict__ uEb) {
    __shared__ __attribute__((aligned(16))) u16 As[2][128 * 64];  // 32 KB
    __shared__ __attribute__((aligned(16))) u16 Bs[2][64 * 64];   // 16 KB
    const int tid = threadIdx.x;
    const int bid = blockIdx.x;                // 2048
    const int bb = bid & 7;                    // batch = XCD
    const int q = bid >> 3;                    // 0..255
    const int ch = q & 1;
    const int rt = q >> 1;                     // 0..127
    const int row0 = bb * E_ + rt * 128;

    const int wv = tid >> 6, l = tid & 63;
    const int fr = l & 15, fg = l >> 4;
    const int lrow0 = wv * 32 + fr;            // 0..127
    const int R0 = row0 + lrow0, R1 = R0 + 16;

    const char* img = (const char*)(WeT2 + (long)ch * 32768);
    const int swz = (fr & 7) << 4;

    auto stage = [&](int kk, int buf) {
        const int seg = kk >> 1, half = kk & 1;
        #pragma unroll
        for (int i = 0; i < 4; ++i) {          // A: 1024 chunks of 16B
            const int gci = i * 256 + tid;
            const int r = gci >> 3, j = gci & 7;
            const int gr = row0 + r;
            const u16* rp;
            if (seg == 0)      rp = edgesB + (long)gr * DD;
            else if (seg == 1) rp = nodesB + ((long)bb * N_ + senders[gr]) * DD;
            else if (seg == 2) rp = nodesB + ((long)bb * N_ + receivers[gr]) * DD;
            else               rp = globB + ((long)bb * G_ + egi[gr]) * DD;
            const char* src = (const char*)rp + half * 128 +
                              ((j * 16) ^ ((r & 7) << 4));
            char* dst = (char*)As[buf] + r * 128 + j * 16;
            __builtin_amdgcn_global_load_lds(
                (const __attribute__((address_space(1))) void*)src,
                (__attribute__((address_space(3))) void*)dst, 16, 0, 0);
        }
        #pragma unroll
        for (int i = 0; i < 2; ++i) {          // B: 512 chunks of 16B
            const int gci = i * 256 + tid;
            const int col = gci >> 3, j = gci & 7;
            const char* src = img + (long)col * 1024 + kk * 128 + j * 16;
            char* dst = (char*)Bs[buf] + col * 128 + j * 16;
            __builtin_amdgcn_global_load_lds(
                (const __attribute__((address_space(1))) void*)src,
                (__attribute__((address_space(3))) void*)dst, 16, 0, 0);
        }
    };

    f32x4 acc0[4], acc1[4];
    const f32x4 fz = {0.f, 0.f, 0.f, 0.f};
    #pragma unroll
    for (int i = 0; i < 4; ++i) { acc0[i] = fz; acc1[i] = fz; }
    s16x4 eres0[4], eres1[4];

    stage(0, 0);
    asm volatile("s_waitcnt vmcnt(0)" ::: "memory");
    __builtin_amdgcn_s_barrier();
    __builtin_amdgcn_sched_barrier(0);

    #pragma unroll
    for (int kk = 0; kk < 8; ++kk) {
        const int buf = kk & 1;
        if (kk < 7) {
            stage(kk + 1, buf ^ 1);            // 6 loads fly across barriers
            __builtin_amdgcn_sched_barrier(0);
            asm volatile("s_waitcnt vmcnt(6)" ::: "memory");  // stage(kk) done
        } else {
            asm volatile("s_waitcnt vmcnt(0)" ::: "memory");
        }
        __builtin_amdgcn_s_barrier();          // tile kk ready (all waves)
        __builtin_amdgcn_sched_barrier(0);     // pin ds_reads below (rule 18)
        __builtin_amdgcn_s_setprio(1);
        #pragma unroll
        for (int ss = 0; ss < 2; ++ss) {
            const int ko = (ss * 64 + fg * 16) ^ swz;
            const short8 a0 = *(const short8*)((char*)As[buf] + lrow0 * 128 + ko);
            const short8 a1 = *(const short8*)((char*)As[buf] + (lrow0 + 16) * 128 + ko);
            #pragma unroll
            for (int nt = 0; nt < 4; ++nt) {
                const short8 b = *(const short8*)((char*)Bs[buf] + (nt * 16 + fr) * 128 + ko);
                acc0[nt] = __builtin_amdgcn_mfma_f32_16x16x32_bf16(b, a0, acc0[nt], 0, 0, 0);
                acc1[nt] = __builtin_amdgcn_mfma_f32_16x16x32_bf16(b, a1, acc1[nt], 0, 0, 0);
            }
        }
        __builtin_amdgcn_s_setprio(0);
        if (kk == ch) {
            #pragma unroll
            for (int nt = 0; nt < 4; ++nt) {
                const int jb = (nt * 32 + fg * 8) ^ swz;
                eres0[nt] = *(const s16x4*)((char*)As[buf] + lrow0 * 128 + jb);
                eres1[nt] = *(const s16x4*)((char*)As[buf] + (lrow0 + 16) * 128 + jb);
            }
        }
        if (kk < 7) {
            __builtin_amdgcn_sched_barrier(0);
            __builtin_amdgcn_s_barrier();      // all waves done reading buf
        }
    }

    // ---- coalesced epilogue via LDS bounce (As -> fp32, Bs -> bf16) ------
    const float wr = w_res[0];
    float* Af = (float*)As;                    // [128 rows][64 f32] (32 KB)
    u16* Bh = (u16*)Bs;                        // [128 rows][64 bf16] (16 KB)
    __syncthreads();                           // all waves done with As/Bs
    const int rs7 = lrow0 & 7;                 // (lrow0+16)&7 identical
    #pragma unroll
    for (int nt = 0; nt < 4; ++nt) {
        const int cb = nt * 16 + fg * 4;       // local col 0..63
        const float4 bv = *(const float4*)(be + ch * 64 + cb);
        const float u00 = fmaxf(acc0[nt][0] + bv.x, 0.f);
        const float u01 = fmaxf(acc0[nt][1] + bv.y, 0.f);
        const float u02 = fmaxf(acc0[nt][2] + bv.z, 0.f);
        const float u03 = fmaxf(acc0[nt][3] + bv.w, 0.f);
        const float u10 = fmaxf(acc1[nt][0] + bv.x, 0.f);
        const float u11 = fmaxf(acc1[nt][1] + bv.y, 0.f);
        const float u12 = fmaxf(acc1[nt][2] + bv.z, 0.f);
        const float u13 = fmaxf(acc1[nt][3] + bv.w, 0.f);
        s16x4 h0, h1;
        h0[0] = (short)f2bf(u00); h0[1] = (short)f2bf(u01);
        h0[2] = (short)f2bf(u02); h0[3] = (short)f2bf(u03);
        h1[0] = (short)f2bf(u10); h1[1] = (short)f2bf(u11);
        h1[2] = (short)f2bf(u12); h1[3] = (short)f2bf(u13);
        float4 o0, o1;
        o0.x = bf2f((u16)eres0[nt][0]) + wr * u00;
        o0.y = bf2f((u16)eres0[nt][1]) + wr * u01;
        o0.z = bf2f((u16)eres0[nt][2]) + wr * u02;
        o0.w = bf2f((u16)eres0[nt][3]) + wr * u03;
        o1.x = bf2f((u16)eres1[nt][0]) + wr * u10;
        o1.y = bf2f((u16)eres1[nt][1]) + wr * u11;
        o1.z = bf2f((u16)eres1[nt][2]) + wr * u12;
        o1.w = bf2f((u16)eres1[nt][3]) + wr * u13;
        const int ck4 = nt * 4 + fg;           // 16B fp32 chunk 0..15
        const int ck8 = nt * 2 + (fg >> 1);    // 16B bf16 chunk 0..7
        const int h4 = (fg & 1) * 4;
        *(float4*)&Af[lrow0 * 64 + ((ck4 ^ rs7) << 2)] = o0;
        *(float4*)&Af[(lrow0 + 16) * 64 + ((ck4 ^ rs7) << 2)] = o1;
        *(s16x4*)&Bh[lrow0 * 64 + ((ck8 ^ (rs7 & 7)) << 3) + h4] = h0;
        *(s16x4*)&Bh[(lrow0 + 16) * 64 + ((ck8 ^ (rs7 & 7)) << 3) + h4] = h1;
    }
    __syncthreads();
    // copy out fp32: 2048 x 16B, rows as 256B contiguous runs
    #pragma unroll
    for (int it = 0; it < 8; ++it) {
        const int g = it * 256 + tid;
        const int r = g >> 4, c4 = g & 15;
        const float4 v = *(const float4*)&Af[r * 64 + ((c4 ^ (r & 7)) << 2)];
        *(float4*)(outE + (long)(row0 + r) * DD + ch * 64 + c4 * 4) = v;
    }
    // copy out bf16: 1024 x 16B, rows as 128B contiguous runs
    #pragma unroll
    for (int it = 0; it < 4; ++it) {
        const int g = it * 256 + tid;
        const int r = g >> 3, c8 = g & 7;
        const short8 v = *(const short8*)&Bh[r * 64 + ((c8 ^ (r & 7)) << 3)];
        *(short8*)(uEb + (long)(row0 + r) * DD + ch * 64 + c8 * 8) = v;
    }
}

// -------- merged: node GEMM (blocks 0..511) + eagg gather (512..2559) -----
__global__ __launch_bounds__(256, 3) void node_agge(
    const u16* __restrict__ nodesB, const u16* __restrict__ uEb,
    const u16* __restrict__ globB, const int* __restrict__ ngi,
    const int* __restrict__ cnt, const int* __restrict__ cur,
    const int* __restrict__ elist,
    const u16* __restrict__ WnT2, const float* __restrict__ bn,
    const float* __restrict__ nodes, const float* __restrict__ w_res,
    float* __restrict__ outN, u16* __restrict__ uNb,
    const int* __restrict__ gcnt_e, const int* __restrict__ gcur_e,
    const int* __restrict__ gelist_e, float* __restrict__ eaggp) {
    __shared__ char smem[64 * 384 * 2];        // 48 KB (union)
    const int tid = threadIdx.x;

    if (blockIdx.x >= 512) {
        float* accl = (float*)smem;
        const int abid = blockIdx.x - 512;     // 0..2047
        const int bg = abid >> 2;
        const int p  = abid & 3;
        const int b = bg >> 6;
        const int c4 = (tid & 31) << 2;
        const int sub = tid >> 5;
        const int m = gcnt_e[bg];
        const int* lp = gelist_e + (long)b * E_ + (gcur_e[bg] - m);
        f32x4 acc = {0.f, 0.f, 0.f, 0.f};
        for (int j = p * 8 + sub; j < m; j += 32) {
            const u16* up = uEb + (long)lp[j] * DD + c4;
            const s16x4 v = *(const s16x4*)up;
            acc[0] += bf2f((u16)v[0]); acc[1] += bf2f((u16)v[1]);
            acc[2] += bf2f((u16)v[2]); acc[3] += bf2f((u16)v[3]);
        }
        *(f32x4*)&accl[sub * 128 + c4] = acc;
        __syncthreads();
        if (tid < 128) {
            float s = 0.f;
            #pragma unroll
            for (int q2 = 0; q2 < 8; ++q2) s += accl[q2 * 128 + tid];
            eaggp[((long)p * BG_ + bg) * DD + tid] = s;
        }
        return;
    }

    u16* Bs = (u16*)smem;                      // [64*384]
    const int bid = blockIdx.x;                // 0..511
    const int bb = bid & 7;
    const int jj = bid >> 3;
    const int ch = jj & 1;
    const int rt = jj >> 1;
    const int row0 = bb * N_ + rt * 128;

    const int wv = tid >> 6, l = tid & 63;
    const int fr = l & 15, fg = l >> 4;
    const int rowbase = row0 + wv * 32;
    const int R0 = rowbase + fr, R1 = R0 + 16;

    {
        const char* wsrc = (const char*)(WnT2 + (long)ch * 24576) + l * 16;
        char* ldst = (char*)Bs;
        #pragma unroll
        for (int i2 = 0; i2 < 12; ++i2) {
            const int off = (wv * 12 + i2) * 1024;
            __builtin_amdgcn_global_load_lds(
                (const __attribute__((address_space(1))) void*)(wsrc + off),
                (__attribute__((address_space(3))) void*)(ldst + off),
                16, 0, 0);
        }
    }

    const u16* pN0 = nodesB + (long)R0 * DD;
    const u16* pN1 = nodesB + (long)R1 * DD;
    const u16* pG0 = globB + ((long)bb * G_ + ngi[R0]) * DD;
    const u16* pG1 = globB + ((long)bb * G_ + ngi[R1]) * DD;
    short8 PN0[4], PN1[4], PG0[4], PG1[4], PA0[4], PA1[4];
    #pragma unroll
    for (int ss = 0; ss < 4; ++ss) {
        PN0[ss] = *(const short8*)(pN0 + ss * 32 + fg * 8);
        PN1[ss] = *(const short8*)(pN1 + ss * 32 + fg * 8);
        PG0[ss] = *(const short8*)(pG0 + ss * 32 + fg * 8);
        PG1[ss] = *(const short8*)(pG1 + ss * 32 + fg * 8);
    }

    {
        float ga[32];
        const int deg0 = cnt[R0];
        const int* lp0 = elist + (long)bb * E_ + (cur[R0] - deg0);
        #pragma unroll
        for (int j = 0; j < 32; ++j) ga[j] = 0.f;
        for (int i = 0; i < deg0; ++i) {
            const u16* up = uEb + (long)lp0[i] * DD + fg * 8;
            #pragma unroll
            for (int ss = 0; ss < 4; ++ss) {
                const short8 v = *(const short8*)(up + ss * 32);
                #pragma unroll
                for (int e2 = 0; e2 < 8; ++e2) ga[ss * 8 + e2] += bf2f((u16)v[e2]);
            }
        }
        #pragma unroll
        for (int ss = 0; ss < 4; ++ss) {
            short8 h;
            #pragma unroll
            for (int e2 = 0; e2 < 8; ++e2) h[e2] = (short)f2bf(ga[ss * 8 + e2]);
            PA0[ss] = h;
        }
        const int deg1 = cnt[R1];
        const int* lp1 = elist + (long)bb * E_ + (cur[R1] - deg1);
        #pragma unroll
        for (int j = 0; j < 32; ++j) ga[j] = 0.f;
        for (int i = 0; i < deg1; ++i) {
            const u16* up = uEb + (long)lp1[i] * DD + fg * 8;
            #pragma unroll
            for (int ss = 0; ss < 4; ++ss) {
                const short8 v = *(const short8*)(up + ss * 32);
                #pragma unroll
                for (int e2 = 0; e2 < 8; ++e2) ga[ss * 8 + e2] += bf2f((u16)v[e2]);
            }
        }
        #pragma unroll
        for (int ss = 0; ss < 4; ++ss) {
            short8 h;
            #pragma unroll
            for (int e2 = 0; e2 < 8; ++e2) h[e2] = (short)f2bf(ga[ss * 8 + e2]);
            PA1[ss] = h;
        }
    }

    f32x4 acc0[4], acc1[4];
    const f32x4 fz = {0.f, 0.f, 0.f, 0.f};
    #pragma unroll
    for (int i = 0; i < 4; ++i) { acc0[i] = fz; acc1[i] = fz; }

    __syncthreads();

    const char* bsp = (const char*)Bs;
    const int swr = (fr & 7) << 4;
    #pragma unroll
    for (int seg = 0; seg < 3; ++seg) {
        __builtin_amdgcn_s_setprio(1);
        #pragma unroll
        for (int ss = 0; ss < 4; ++ss) {
            const short8 a0 = (seg == 0) ? PN0[ss] : (seg == 1) ? PA0[ss] : PG0[ss];
            const short8 a1 = (seg == 0) ? PN1[ss] : (seg == 1) ? PA1[ss] : PG1[ss];
            #pragma unroll
            for (int nt = 0; nt < 4; ++nt) {
                const int addr = (nt * 16 + fr) * 768 +
                                 ((seg * 256 + ss * 64 + fg * 16) ^ swr);
                const short8 b = *(const short8*)(bsp + addr);
                acc0[nt] = __builtin_amdgcn_mfma_f32_16x16x32_bf16(b, a0, acc0[nt], 0, 0, 0);
                acc1[nt] = __builtin_amdgcn_mfma_f32_16x16x32_bf16(b, a1, acc1[nt], 0, 0, 0);
            }
        }
        __builtin_amdgcn_s_setprio(0);
    }

    const float wr = w_res[0];
    #pragma unroll
    for (int nt = 0; nt < 4; ++nt) {
        const int c = ch * 64 + nt * 16 + fg * 4;
        const float4 bv = *(const float4*)(bn + c);
        const float4 n0 = *(const float4*)(nodes + (long)R0 * DD + c);
        const float4 n1 = *(const float4*)(nodes + (long)R1 * DD + c);
        const float u00 = fmaxf(acc0[nt][0] + bv.x, 0.f);
        const float u01 = fmaxf(acc0[nt][1] + bv.y, 0.f);
        const float u02 = fmaxf(acc0[nt][2] + bv.z, 0.f);
        const float u03 = fmaxf(acc0[nt][3] + bv.w, 0.f);
        const float u10 = fmaxf(acc1[nt][0] + bv.x, 0.f);
        const float u11 = fmaxf(acc1[nt][1] + bv.y, 0.f);
        const float u12 = fmaxf(acc1[nt][2] + bv.z, 0.f);
        const float u13 = fmaxf(acc1[nt][3] + bv.w, 0.f);
        s16x4 h0, h1;
        h0[0] = (short)f2bf(u00); h0[1] = (short)f2bf(u01);
        h0[2] = (short)f2bf(u02); h0[3] = (short)f2bf(u03);
        h1[0] = (short)f2bf(u10); h1[1] = (short)f2bf(u11);
        h1[2] = (short)f2bf(u12); h1[3] = (short)f2bf(u13);
        *(s16x4*)(uNb + (long)R0 * DD + c) = h0;
        *(s16x4*)(uNb + (long)R1 * DD + c) = h1;
        float4 o0, o1;
        o0.x = n0.x + wr * u00; o0.y = n0.y + wr * u01;
        o0.z = n0.z + wr * u02; o0.w = n0.w + wr * u03;
        o1.x = n1.x + wr * u10; o1.y = n1.y + wr * u11;
        o1.z = n1.z + wr * u12; o1.w = n1.w + wr * u13;
        *(float4*)(outN + (long)R0 * DD + c) = o0;
        *(float4*)(outN + (long)R1 * DD + c) = o1;
    }
}

// -------- agg = per-(b,g) gather-sum of bf16 u rows (node aggregate) ------
__global__ __launch_bounds__(256) void agg_only(
    const int* __restrict__ gcnt, const int* __restrict__ gcur,
    const int* __restrict__ gelist, int spb, const u16* __restrict__ uB,
    float* __restrict__ aggp /* [PART][BG][DD] */) {
    __shared__ float accl[1024];
    const int bg = blockIdx.x >> 2;            // grid = BG*PART
    const int p  = blockIdx.x & 3;
    const int b = bg >> 6;
    const int tid = threadIdx.x;
    const int c4 = (tid & 31) << 2;
    const int sub = tid >> 5;                  // 0..7
    const int m = gcnt[bg];
    const int* lp = gelist + (long)b * spb + (gcur[bg] - m);
    f32x4 acc = {0.f, 0.f, 0.f, 0.f};
    for (int j = p * 8 + sub; j < m; j += 32) {
        const u16* up = uB + (long)lp[j] * DD + c4;
        const s16x4 v = *(const s16x4*)up;
        acc[0] += bf2f((u16)v[0]); acc[1] += bf2f((u16)v[1]);
        acc[2] += bf2f((u16)v[2]); acc[3] += bf2f((u16)v[3]);
    }
    *(f32x4*)&accl[sub * 128 + c4] = acc;
    __syncthreads();
    if (tid < 128) {
        float s = 0.f;
        #pragma unroll
        for (int q2 = 0; q2 < 8; ++q2) s += accl[q2 * 128 + tid];
        aggp[((long)p * BG_ + bg) * DD + tid] = s;
    }
}

// ---------------- global block: 512 rows, K=384, fp32 VALU ----------------
__global__ __launch_bounds__(128) void global_block(
    const float* __restrict__ naggp, const float* __restrict__ eaggp,
    const float* __restrict__ glob,
    const float* __restrict__ Wg, const float* __restrict__ bgb,
    const float* __restrict__ w_res, float* __restrict__ out) {
    __shared__ float gin[384];
    const int row = blockIdx.x;
    const int tid = threadIdx.x;
    float sn = 0.f, se = 0.f;
    #pragma unroll
    for (int p = 0; p < PART; ++p) {
        sn += naggp[((long)p * BG_ + row) * DD + tid];
        se += eaggp[((long)p * BG_ + row) * DD + tid];
    }
    gin[tid]       = sn;
    gin[128 + tid] = se;
    gin[256 + tid] = glob[row * DD + tid];
    __syncthreads();
    float acc = bgb[tid];
    #pragma unroll 4
    for (int k = 0; k < 384; ++k) acc += gin[k] * Wg[k * DD + tid];
    const float upd = fmaxf(acc, 0.f);
    out[OFF_GLOB + row * DD + tid] = glob[row * DD + tid] + w_res[0] * upd;
}

extern "C" void kernel_launch(void* const* d_in, const int* in_sizes, int n_in,
                              void* d_out, int out_size, void* d_ws, size_t ws_size,
                              hipStream_t stream) {
    const float* nodes     = (const float*)d_in[0];
    const float* edges     = (const float*)d_in[1];
    const int*   receivers = (const int*)d_in[2];
    const int*   senders   = (const int*)d_in[3];
    const float* glob      = (const float*)d_in[4];
    const int*   ngi       = (const int*)d_in[5];
    const int*   egi       = (const int*)d_in[6];
    const float* We        = (const float*)d_in[7];
    const float* be        = (const float*)d_in[8];
    const float* Wn        = (const float*)d_in[9];
    const float* bn        = (const float*)d_in[10];
    const float* Wg        = (const float*)d_in[11];
    const float* bg        = (const float*)d_in[12];
    const float* w_res     = (const float*)d_in[13];
    float* out = (float*)d_out;
    float* ws  = (float*)d_ws;

    float* eaggp = ws + WS_EAGGP;
    float* naggp = ws + WS_NAGGP;
    int* cnt      = (int*)(ws + WS_CNT);
    int* gcnt_e   = (int*)(ws + WS_GCNTE);
    int* gcnt_n   = (int*)(ws + WS_GCNTN);
    int* cur      = (int*)(ws + WS_CUR);
    int* gcur_e   = (int*)(ws + WS_GCURE);
    int* gcur_n   = (int*)(ws + WS_GCURN);
    int* elist    = (int*)(ws + WS_ELIST);
    int* gelist_e = (int*)(ws + WS_GELE);
    int* gelist_n = (int*)(ws + WS_GELN);
    u16* nodesB = (u16*)(ws + WS_NODB);
    u16* globB  = (u16*)(ws + WS_GLOBB);
    u16* WeT2   = (u16*)(ws + WS_WET);
    u16* WnT2   = (u16*)(ws + WS_WNT);
    u16* uEb    = (u16*)(ws + WS_UEB);
    u16* edgesB = (u16*)(ws + WS_EDGB);
    u16* uNb    = (u16*)(ws + WS_EDGB);  // reuses edgesB region (consumed)

    float* outE = out + OFF_EDGES;
    float* outN = out + OFF_NODES;

    hipMemsetAsync(cnt, 0, (size_t)(BN_ + 1024) * sizeof(int), stream);

    hipLaunchKernelGGL(prep_all, dim3(RE_END / 256), dim3(256), 0, stream,
                       We, Wn, WeT2, WnT2, nodes, glob, edges,
                       nodesB, globB, edgesB,
                       receivers, senders, ngi, egi, out,
                       cnt, gcnt_e, gcnt_n);
    hipLaunchKernelGGL(k_scan, dim3(8), dim3(1024), 0, stream,
                       cnt, cur, gcnt_e, gcur_e, gcnt_n, gcur_n);
    hipLaunchKernelGGL(k_fill_all, dim3(512), dim3(256), 0, stream,
                       receivers, egi, ngi, cur, elist, gcur_e, gelist_e,
                       gcur_n, gelist_n);
    hipLaunchKernelGGL(edge_mfma, dim3(2048), dim3(256), 0, stream,
                       edgesB, nodesB, globB, receivers, senders, egi,
                       WeT2, be, w_res, outE, uEb);
    hipLaunchKernelGGL(node_agge, dim3(2560), dim3(256), 0, stream,
                       nodesB, uEb, globB, ngi, cnt, cur, elist,
                       WnT2, bn, nodes, w_res, outN, uNb,
                       gcnt_e, gcur_e, gelist_e, eaggp);
    hipLaunchKernelGGL(agg_only, dim3(BG_ * PART), dim3(256), 0, stream,
                       gcnt_n, gcur_n, gelist_n, N_, uNb, naggp);
    hipLaunchKernelGGL(global_block, dim3(BG_), dim3(128), 0, stream,
                       naggp, eaggp, glob, Wg, bg, w_res, out);
}